// Round 2
// baseline (3422.233 us; speedup 1.0000x reference)
//
#include <hip/hip_runtime.h>
#include <cmath>

// ---------- constants ----------
#define IMG 131072        // 512*256 per batch image
#define BIGF 1048576      // 8*512*256

#define CF_RELU 1
#define CF_RES  2
#define CF_BN   4

__device__ __forceinline__ float wave_sum(float v){
    #pragma unroll
    for (int off = 32; off; off >>= 1) v += __shfl_xor(v, off);
    return v;
}

// ---------- GAP: mean over 256 spatial ----------
__global__ __launch_bounds__(64) void k_gap(const float* __restrict__ x, float* __restrict__ out){
    const int bc = blockIdx.x;           // b*512 + c
    const int lane = threadIdx.x;
    const float* p = x + (size_t)bc * 256;
    float s = p[lane] + p[lane + 64] + p[lane + 128] + p[lane + 192];
    s = wave_sum(s);
    if (lane == 0) out[bc] = s * (1.0f / 256.0f);
}

// ---------- tiny GEMM: out[8,O] = in[8,512] @ W[O,512]^T + bias (+add) ----------
__global__ __launch_bounds__(64) void k_gemm8(
    const float* __restrict__ in, const float* __restrict__ W,
    const float* __restrict__ bias, const float* __restrict__ add,
    int add_off, int add_stride, float* __restrict__ out, int O, int relu)
{
    const int o = blockIdx.x;
    const int lane = threadIdx.x;
    const float* wr = W + (size_t)o * 512;
    float acc[8] = {0,0,0,0,0,0,0,0};
    #pragma unroll
    for (int i = 0; i < 8; i++){
        float w = wr[lane + 64*i];
        #pragma unroll
        for (int b = 0; b < 8; b++) acc[b] += w * in[b*512 + lane + 64*i];
    }
    #pragma unroll
    for (int b = 0; b < 8; b++) acc[b] = wave_sum(acc[b]);
    if (lane < 8){
        float v = acc[0];
        #pragma unroll
        for (int b = 1; b < 8; b++) if (lane == b) v = acc[b];
        v += bias[o];
        if (add) v += add[lane*add_stride + add_off + o];
        if (relu) v = fmaxf(v, 0.f);
        out[(size_t)lane * O + o] = v;
    }
}

// ---------- asri batch-axis attention; writes merged o [8,512] ----------
__global__ __launch_bounds__(64) void k_asri_attn(const float* __restrict__ qkv, float* __restrict__ om){
    const int h = blockIdx.x >> 3, b = blockIdx.x & 7, c = threadIdx.x;
    const int ci = c*8 + h;
    float qc = qkv[b*2048 + ci];            // slice 0 = q
    float s[8];
    #pragma unroll
    for (int d = 0; d < 8; d++){
        float p = qc * qkv[d*2048 + 512 + ci];   // slice 1 = k
        p = wave_sum(p);
        s[d] = p * 0.125f;                       // SCALE = 64^-0.5
    }
    float m = s[0];
    #pragma unroll
    for (int d = 1; d < 8; d++) m = fmaxf(m, s[d]);
    float sum = 0.f;
    #pragma unroll
    for (int d = 0; d < 8; d++){ s[d] = __expf(s[d]-m); sum += s[d]; }
    float r = 1.f / sum;
    float oc = 0.f;
    #pragma unroll
    for (int d = 0; d < 8; d++) oc += s[d]*r * qkv[d*2048 + 1024 + ci];  // slice 2 = v
    om[b*512 + ci] = oc;
}

// ---------- LN over 512, 8 rows ----------
__global__ __launch_bounds__(64) void k_ln8(const float* __restrict__ in,
    const float* __restrict__ g, const float* __restrict__ be, float* __restrict__ out)
{
    const int b = blockIdx.x, lane = threadIdx.x;
    float v[8]; float s = 0.f;
    #pragma unroll
    for (int i = 0; i < 8; i++){ v[i] = in[b*512 + lane + 64*i]; s += v[i]; }
    s = wave_sum(s);
    float mean = s * (1.f/512.f);
    float q = 0.f;
    #pragma unroll
    for (int i = 0; i < 8; i++){ float d = v[i]-mean; q += d*d; }
    q = wave_sum(q);
    float rstd = rsqrtf(q*(1.f/512.f) + 1e-5f);
    #pragma unroll
    for (int i = 0; i < 8; i++){
        int c = lane + 64*i;
        out[b*512 + c] = (v[i]-mean)*rstd*g[c] + be[c];
    }
}

// ---------- bilinear upsample 4x4 -> 16x16 align_corners ----------
__global__ __launch_bounds__(256) void k_up(const float* __restrict__ s, float* __restrict__ out){
    const int idx = blockIdx.x*256 + threadIdx.x;       // b*512*256 + ch*256 + y*16 + x
    const int x = idx & 15, y = (idx >> 4) & 15, bc = idx >> 8;
    float px = (float)(x*3) / 15.0f, py = (float)(y*3) / 15.0f;  // matches ref float32 arith
    int lx = (int)px, ly = (int)py;
    float wx = px - lx, wy = py - ly;
    int hx = min(lx+1, 3), hy = min(ly+1, 3);
    const float* p = s + (size_t)bc * 16;
    float v00 = p[ly*4+lx], v01 = p[ly*4+hx], v10 = p[hy*4+lx], v11 = p[hy*4+hx];
    float a0 = v00*(1.f-wy) + v10*wy;
    float a1 = v01*(1.f-wy) + v11*wy;
    out[idx] = a0*(1.f-wx) + a1*wx;
}

// ---------- conv1x1 as per-batch GEMM: out[b][o][n] = epi(sum_c W[o][c]*X[b][c][n]) ----------
__global__ __launch_bounds__(256) void k_conv(
    const float* __restrict__ X, const float* __restrict__ W,
    const float* __restrict__ bias, const float* __restrict__ res,
    const float* __restrict__ bng, const float* __restrict__ bnb, float bninv,
    float* __restrict__ out, int flags)
{
    __shared__ float sW[16][64];
    __shared__ float sX[16][64];
    const int b = blockIdx.z, o0 = blockIdx.y*64, n0 = blockIdx.x*64;
    const int tid = threadIdx.x;
    const int tx = tid & 15, ty = tid >> 4;
    const float* Xb = X + (size_t)b * IMG;
    const int lo  = tid >> 2;
    const int lk4 = (tid & 3) << 2;
    const int lkx = tid >> 4;
    const int ln4 = (tid & 15) << 2;
    float acc[4][4] = {};
    for (int k0 = 0; k0 < 512; k0 += 16){
        float4 w4 = *(const float4*)(W  + (size_t)(o0+lo)*512 + k0 + lk4);
        float4 x4 = *(const float4*)(Xb + (size_t)(k0+lkx)*256 + n0 + ln4);
        __syncthreads();
        sW[lk4+0][lo] = w4.x; sW[lk4+1][lo] = w4.y; sW[lk4+2][lo] = w4.z; sW[lk4+3][lo] = w4.w;
        *(float4*)&sX[lkx][ln4] = x4;
        __syncthreads();
        #pragma unroll
        for (int k = 0; k < 16; k++){
            float4 av = *(const float4*)&sW[k][ty*4];
            float4 bv = *(const float4*)&sX[k][tx*4];
            float aa[4] = {av.x, av.y, av.z, av.w};
            float bb[4] = {bv.x, bv.y, bv.z, bv.w};
            #pragma unroll
            for (int i = 0; i < 4; i++)
                #pragma unroll
                for (int j = 0; j < 4; j++) acc[i][j] += aa[i]*bb[j];
        }
    }
    #pragma unroll
    for (int i = 0; i < 4; i++){
        const int o = o0 + ty*4 + i;
        const float bi = bias[o];
        float sc = 1.f, sh = 0.f;
        if (flags & CF_BN){ sc = bninv*bng[o]; sh = bnb[o]; }
        float t[4];
        #pragma unroll
        for (int j = 0; j < 4; j++){
            float v = acc[i][j] + bi;
            if (flags & CF_BN)   v = v*sc + sh;
            if (flags & CF_RELU) v = fmaxf(v, 0.f);
            t[j] = v;
        }
        size_t base = (size_t)b*IMG + (size_t)o*256 + n0 + tx*4;
        if (flags & CF_RES){
            float4 r4 = *(const float4*)(res + base);
            t[0]+=r4.x; t[1]+=r4.y; t[2]+=r4.z; t[3]+=r4.w;
        }
        *(float4*)(out + base) = make_float4(t[0], t[1], t[2], t[3]);
    }
}

// ---------- sscm attention weights [h][b][d] ----------
__global__ __launch_bounds__(64) void k_sscm_attn(const float* __restrict__ q8,
    const float* __restrict__ k8, float* __restrict__ attnw)
{
    const int h = blockIdx.x >> 3, b = blockIdx.x & 7, c = threadIdx.x;
    const int ci = c*8 + h;
    float qc = q8[b*512 + ci];
    float s[8];
    #pragma unroll
    for (int d = 0; d < 8; d++){
        float p = qc * k8[d*512 + ci];
        p = wave_sum(p);
        s[d] = p * 0.125f;
    }
    float m = s[0];
    #pragma unroll
    for (int d = 1; d < 8; d++) m = fmaxf(m, s[d]);
    float sum = 0.f;
    #pragma unroll
    for (int d = 0; d < 8; d++){ s[d] = __expf(s[d]-m); sum += s[d]; }
    float r = 1.f/sum;
    if (c < 8){
        float v = s[0];
        #pragma unroll
        for (int d = 1; d < 8; d++) if (c == d) v = s[d];
        attnw[blockIdx.x*8 + c] = v*r;
    }
}

// ---------- sscm apply: out[b][e][pix] = sum_d attnw[e%8][b][d] * v[d][e][pix] ----------
__global__ __launch_bounds__(256) void k_sscm_apply(const float* __restrict__ attnw,
    const float* __restrict__ v, float* __restrict__ out)
{
    const int idx = blockIdx.x*256 + threadIdx.x;
    const int pix = idx & 255, e = (idx >> 8) & 511, b = idx >> 17;
    const int h = e & 7;
    const float* aw = attnw + (h*8 + b)*8;
    float acc = 0.f;
    #pragma unroll
    for (int d = 0; d < 8; d++) acc += aw[d] * v[(size_t)d*IMG + (size_t)e*256 + pix];
    out[idx] = acc;
}

// ---------- pixel cross-batch attention (fused, per (ntile,b,h)) ----------
__global__ __launch_bounds__(256) void k_pixel_attn(
    const float* __restrict__ Q, const float* __restrict__ K,
    const float* __restrict__ V, float* __restrict__ O)
{
    __shared__ float QT[64][32];    // [c][nl]
    __shared__ float S[32][256];    // [nl][m]
    __shared__ float KV[64][64];    // [c][ml]  (K^T then V^T tiles)
    const int nt = blockIdx.x, b = blockIdx.y, h = blockIdx.z;
    const int tid = threadIdx.x;
    const int n0 = nt * 32;
    const int tx = tid & 15, ty = tid >> 4;

    #pragma unroll
    for (int i = 0; i < 8; i++){
        int fl = i*256 + tid;
        int c = fl >> 5, nl = fl & 31;
        QT[c][nl] = Q[(size_t)b*IMG + (size_t)(c*8+h)*256 + n0 + nl];
    }
    float oacc[2][4] = {};
    for (int d = 0; d < 8; d++){
        // S[n][m] = sum_c QT[c][n] * K^T[c][m]   (NO scale -- matches source)
        for (int mt = 0; mt < 4; mt++){
            __syncthreads();
            #pragma unroll
            for (int i = 0; i < 16; i++){
                int fl = i*256 + tid;
                int c = fl >> 6, ml = fl & 63;
                KV[c][ml] = K[(size_t)d*IMG + (size_t)(c*8+h)*256 + mt*64 + ml];
            }
            __syncthreads();
            float s0[4] = {0,0,0,0}, s1[4] = {0,0,0,0};
            #pragma unroll
            for (int c = 0; c < 64; c++){
                float2 q2 = *(const float2*)&QT[c][ty*2];
                float4 k4 = *(const float4*)&KV[c][tx*4];
                float kk[4] = {k4.x,k4.y,k4.z,k4.w};
                #pragma unroll
                for (int j = 0; j < 4; j++){ s0[j] += q2.x*kk[j]; s1[j] += q2.y*kk[j]; }
            }
            *(float4*)&S[ty*2+0][mt*64 + tx*4] = make_float4(s0[0],s0[1],s0[2],s0[3]);
            *(float4*)&S[ty*2+1][mt*64 + tx*4] = make_float4(s1[0],s1[1],s1[2],s1[3]);
        }
        __syncthreads();
        // softmax over m in [0,256) per row (per key-batch d block)
        {
            const int row = tid >> 3, seg = tid & 7;
            float* sr = &S[row][seg*32];
            float mx = -3.4e38f;
            #pragma unroll
            for (int m = 0; m < 32; m++) mx = fmaxf(mx, sr[m]);
            mx = fmaxf(mx, __shfl_xor(mx,1));
            mx = fmaxf(mx, __shfl_xor(mx,2));
            mx = fmaxf(mx, __shfl_xor(mx,4));
            float sum = 0.f;
            #pragma unroll
            for (int m = 0; m < 32; m++){ float e = __expf(sr[m]-mx); sr[m] = e; sum += e; }
            sum += __shfl_xor(sum,1);
            sum += __shfl_xor(sum,2);
            sum += __shfl_xor(sum,4);
            float r = 1.f/sum;
            #pragma unroll
            for (int m = 0; m < 32; m++) sr[m] *= r;
        }
        __syncthreads();
        // O += P @ V  (V^T staged per m-tile)
        for (int mt = 0; mt < 4; mt++){
            #pragma unroll
            for (int i = 0; i < 16; i++){
                int fl = i*256 + tid;
                int c = fl >> 6, ml = fl & 63;
                KV[c][ml] = V[(size_t)d*IMG + (size_t)(c*8+h)*256 + mt*64 + ml];
            }
            __syncthreads();
            #pragma unroll
            for (int ml = 0; ml < 64; ml += 4){
                float4 p0 = *(const float4*)&S[ty*2+0][mt*64 + ml];
                float4 p1 = *(const float4*)&S[ty*2+1][mt*64 + ml];
                #pragma unroll
                for (int j = 0; j < 4; j++){
                    float4 v4 = *(const float4*)&KV[tx*4+j][ml];
                    oacc[0][j] += p0.x*v4.x + p0.y*v4.y + p0.z*v4.z + p0.w*v4.w;
                    oacc[1][j] += p1.x*v4.x + p1.y*v4.y + p1.z*v4.z + p1.w*v4.w;
                }
            }
            __syncthreads();
        }
    }
    #pragma unroll
    for (int j = 0; j < 4; j++){
        const int c = tx*4 + j;
        size_t base = (size_t)b*IMG + (size_t)(c*8+h)*256 + n0;
        O[base + ty*2 + 0] = oacc[0][j];
        O[base + ty*2 + 1] = oacc[1][j];
    }
}

// ---------- LN over channels (strided), keeps [b][c][n] layout ----------
__global__ __launch_bounds__(64) void k_ln_pix(const float* __restrict__ in,
    const float* __restrict__ g, const float* __restrict__ be, float* __restrict__ out)
{
    const int bn = blockIdx.x;                 // b*256 + n
    const int b = bn >> 8, n = bn & 255;
    const int lane = threadIdx.x;
    const float* p = in + (size_t)b*IMG + n;
    float v[8]; float s = 0.f;
    #pragma unroll
    for (int i = 0; i < 8; i++){ v[i] = p[(size_t)(lane + 64*i)*256]; s += v[i]; }
    s = wave_sum(s);
    float mean = s * (1.f/512.f);
    float q = 0.f;
    #pragma unroll
    for (int i = 0; i < 8; i++){ float d = v[i]-mean; q += d*d; }
    q = wave_sum(q);
    float rstd = rsqrtf(q*(1.f/512.f) + 1e-5f);
    #pragma unroll
    for (int i = 0; i < 8; i++){
        int c = lane + 64*i;
        out[(size_t)b*IMG + (size_t)c*256 + n] = (v[i]-mean)*rstd*g[c] + be[c];
    }
}

// ---------- host orchestration ----------
extern "C" void kernel_launch(void* const* d_in, const int* in_sizes, int n_in,
                              void* d_out, int out_size, void* d_ws, size_t ws_size,
                              hipStream_t stream)
{
    const float* xs    = (const float*)d_in[0];
    const float* xq    = (const float*)d_in[1];
    const float* qkvw  = (const float*)d_in[2];  const float* qkvb = (const float*)d_in[3];
    const float* paw   = (const float*)d_in[4];  const float* pab  = (const float*)d_in[5];
    const float* ln1g  = (const float*)d_in[6];  const float* ln1b = (const float*)d_in[7];
    const float* f1w   = (const float*)d_in[8];  const float* f1b  = (const float*)d_in[9];
    const float* f2w   = (const float*)d_in[10]; const float* f2b  = (const float*)d_in[11];
    const float* ln2g  = (const float*)d_in[12]; const float* ln2b = (const float*)d_in[13];
    const float* c1w   = (const float*)d_in[14]; const float* c1b  = (const float*)d_in[15];
    const float* c2w   = (const float*)d_in[16]; const float* c2b  = (const float*)d_in[17];
    const float* bng   = (const float*)d_in[18]; const float* bnb  = (const float*)d_in[19];
    const float* caqw  = (const float*)d_in[20]; const float* caqb = (const float*)d_in[21];
    const float* cakw  = (const float*)d_in[22]; const float* cakb = (const float*)d_in[23];
    const float* cavw  = (const float*)d_in[24]; const float* cavb = (const float*)d_in[25];
    const float* capw  = (const float*)d_in[26]; const float* capb = (const float*)d_in[27];
    const float* pqw   = (const float*)d_in[28]; const float* pqb  = (const float*)d_in[29];
    const float* pkw   = (const float*)d_in[30]; const float* pkb  = (const float*)d_in[31];
    const float* pvw   = (const float*)d_in[32]; const float* pvb  = (const float*)d_in[33];
    const float* ppw   = (const float*)d_in[34]; const float* ppb  = (const float*)d_in[35];
    const float* plng  = (const float*)d_in[36]; const float* plnb = (const float*)d_in[37];
    const float* plinw = (const float*)d_in[38]; const float* plinb= (const float*)d_in[39];

    float* ws = (float*)d_ws;
    float* sa_s = ws;
    float* sa_q = ws + 1*(size_t)BIGF;
    float* ca_s = ws + 2*(size_t)BIGF;
    float* ca_q = ws + 3*(size_t)BIGF;
    float* tA   = ws + 4*(size_t)BIGF;
    float* tB   = ws + 5*(size_t)BIGF;
    float* tC   = ws + 6*(size_t)BIGF;
    float* tD   = ws + 7*(size_t)BIGF;
    float* tE   = ws + 8*(size_t)BIGF;
    float* sm   = ws + 9*(size_t)BIGF;
    float* gap  = sm;            // 4096
    float* qkv  = sm + 4096;     // 16384
    float* om   = sm + 20480;    // 4096
    float* aa   = sm + 24576;    // 4096
    float* hb   = sm + 28672;    // 4096
    float* a2   = sm + 32768;    // 4096
    float* lnb_ = sm + 36864;    // 4096
    float* s8   = sm + 40960;    // 65536
    float* attnw= sm + 106496;   // 512
    float* q8   = sm + 107008;   // 4096
    float* k8   = sm + 111104;   // 4096

    const float bninv = 1.0f / sqrtf(1.0f + 1e-5f);
    const dim3 cgrid(4, 8, 8);

    auto asri = [&](const float* x, float* out){
        k_gap<<<4096, 64, 0, stream>>>(x, gap);
        k_gemm8<<<2048, 64, 0, stream>>>(gap, qkvw, qkvb, nullptr, 0, 0, qkv, 2048, 0);
        k_asri_attn<<<64, 64, 0, stream>>>(qkv, om);
        k_gemm8<<<512, 64, 0, stream>>>(om, paw, pab, qkv, 1536, 2048, aa, 512, 0);
        k_ln8<<<8, 64, 0, stream>>>(aa, ln1g, ln1b, lnb_);
        k_gemm8<<<512, 64, 0, stream>>>(lnb_, f1w, f1b, nullptr, 0, 0, hb, 512, 1);
        k_gemm8<<<512, 64, 0, stream>>>(hb, f2w, f2b, aa, 0, 512, a2, 512, 0);
        k_ln8<<<8, 64, 0, stream>>>(a2, ln2g, ln2b, lnb_);
        k_gemm8<<<8192, 64, 0, stream>>>(lnb_, c1w, c1b, nullptr, 0, 0, s8, 8192, 0);
        k_up<<<4096, 256, 0, stream>>>(s8, tA);   // FIX: 4096 blocks (was 2048 -> batches 4..7 were garbage)
        k_conv<<<cgrid, 256, 0, stream>>>(tA, c2w, c2b, x, bng, bnb, bninv, out,
                                          CF_BN | CF_RELU | CF_RES);
    };
    asri(xs, sa_s);
    asri(xq, sa_q);

    auto sscm = [&](const float* x1, const float* x2, float* out){
        k_gap<<<4096, 64, 0, stream>>>(x1, gap);
        k_gemm8<<<512, 64, 0, stream>>>(gap, caqw, caqb, nullptr, 0, 0, q8, 512, 0);
        k_gap<<<4096, 64, 0, stream>>>(x2, gap);
        k_gemm8<<<512, 64, 0, stream>>>(gap, cakw, cakb, nullptr, 0, 0, k8, 512, 0);
        k_sscm_attn<<<64, 64, 0, stream>>>(q8, k8, attnw);
        k_conv<<<cgrid, 256, 0, stream>>>(x2, cavw, cavb, nullptr, nullptr, nullptr, 1.f, tA, 0);
        k_sscm_apply<<<4096, 256, 0, stream>>>(attnw, tA, tB);
        k_conv<<<cgrid, 256, 0, stream>>>(tB, capw, capb, nullptr, nullptr, nullptr, 1.f, out, CF_RELU);
    };
    sscm(sa_s, sa_q, ca_s);
    sscm(sa_q, sa_s, ca_q);

    auto pixel = [&](const float* x1, const float* x2, float* out){
        k_conv<<<cgrid, 256, 0, stream>>>(x1, pqw, pqb, nullptr, nullptr, nullptr, 1.f, tA, 0);
        k_conv<<<cgrid, 256, 0, stream>>>(x2, pkw, pkb, nullptr, nullptr, nullptr, 1.f, tB, 0);
        k_conv<<<cgrid, 256, 0, stream>>>(x2, pvw, pvb, nullptr, nullptr, nullptr, 1.f, tC, 0);
        k_pixel_attn<<<dim3(8, 8, 8), 256, 0, stream>>>(tA, tB, tC, tD);
        k_conv<<<cgrid, 256, 0, stream>>>(tD, ppw, ppb, x1, nullptr, nullptr, 1.f, tE, CF_RES);
        k_ln_pix<<<2048, 64, 0, stream>>>(tE, plng, plnb, tA);
        k_conv<<<cgrid, 256, 0, stream>>>(tA, plinw, plinb, nullptr, nullptr, nullptr, 1.f, out, CF_RELU);
    };
    float* out0 = (float*)d_out;
    pixel(sa_s, ca_q, out0);
    pixel(sa_q, ca_s, out0 + (size_t)BIGF);

    (void)in_sizes; (void)n_in; (void)out_size; (void)ws_size;
}

// Round 3
// 1257.013 us; speedup vs baseline: 2.7225x; 2.7225x over previous
//
#include <hip/hip_runtime.h>
#include <cmath>

// ---------- constants ----------
#define IMG 131072        // 512*256 per batch image
#define BIGF 1048576      // 8*512*256

#define CF_RELU 1
#define CF_RES  2
#define CF_BN   4

__device__ __forceinline__ float wave_sum(float v){
    #pragma unroll
    for (int off = 32; off; off >>= 1) v += __shfl_xor(v, off);
    return v;
}

// ---------- GAP: mean over 256 spatial ----------
__global__ __launch_bounds__(64) void k_gap(const float* __restrict__ x, float* __restrict__ out){
    const int bc = blockIdx.x;           // b*512 + c
    const int lane = threadIdx.x;
    const float* p = x + (size_t)bc * 256;
    float s = p[lane] + p[lane + 64] + p[lane + 128] + p[lane + 192];
    s = wave_sum(s);
    if (lane == 0) out[bc] = s * (1.0f / 256.0f);
}

// ---------- tiny GEMM: out[8,O] = in[8,512] @ W[O,512]^T + bias (+add) ----------
__global__ __launch_bounds__(64) void k_gemm8(
    const float* __restrict__ in, const float* __restrict__ W,
    const float* __restrict__ bias, const float* __restrict__ add,
    int add_off, int add_stride, float* __restrict__ out, int O, int relu)
{
    const int o = blockIdx.x;
    const int lane = threadIdx.x;
    const float* wr = W + (size_t)o * 512;
    float acc[8] = {0,0,0,0,0,0,0,0};
    #pragma unroll
    for (int i = 0; i < 8; i++){
        float w = wr[lane + 64*i];
        #pragma unroll
        for (int b = 0; b < 8; b++) acc[b] += w * in[b*512 + lane + 64*i];
    }
    #pragma unroll
    for (int b = 0; b < 8; b++) acc[b] = wave_sum(acc[b]);
    if (lane < 8){
        float v = acc[0];
        #pragma unroll
        for (int b = 1; b < 8; b++) if (lane == b) v = acc[b];
        v += bias[o];
        if (add) v += add[lane*add_stride + add_off + o];
        if (relu) v = fmaxf(v, 0.f);
        out[(size_t)lane * O + o] = v;
    }
}

// ---------- asri batch-axis attention; writes merged o [8,512] ----------
__global__ __launch_bounds__(64) void k_asri_attn(const float* __restrict__ qkv, float* __restrict__ om){
    const int h = blockIdx.x >> 3, b = blockIdx.x & 7, c = threadIdx.x;
    const int ci = c*8 + h;
    float qc = qkv[b*2048 + ci];            // slice 0 = q
    float s[8];
    #pragma unroll
    for (int d = 0; d < 8; d++){
        float p = qc * qkv[d*2048 + 512 + ci];   // slice 1 = k
        p = wave_sum(p);
        s[d] = p * 0.125f;                       // SCALE = 64^-0.5
    }
    float m = s[0];
    #pragma unroll
    for (int d = 1; d < 8; d++) m = fmaxf(m, s[d]);
    float sum = 0.f;
    #pragma unroll
    for (int d = 0; d < 8; d++){ s[d] = __expf(s[d]-m); sum += s[d]; }
    float r = 1.f / sum;
    float oc = 0.f;
    #pragma unroll
    for (int d = 0; d < 8; d++) oc += s[d]*r * qkv[d*2048 + 1024 + ci];  // slice 2 = v
    om[b*512 + ci] = oc;
}

// ---------- LN over 512, 8 rows ----------
__global__ __launch_bounds__(64) void k_ln8(const float* __restrict__ in,
    const float* __restrict__ g, const float* __restrict__ be, float* __restrict__ out)
{
    const int b = blockIdx.x, lane = threadIdx.x;
    float v[8]; float s = 0.f;
    #pragma unroll
    for (int i = 0; i < 8; i++){ v[i] = in[b*512 + lane + 64*i]; s += v[i]; }
    s = wave_sum(s);
    float mean = s * (1.f/512.f);
    float q = 0.f;
    #pragma unroll
    for (int i = 0; i < 8; i++){ float d = v[i]-mean; q += d*d; }
    q = wave_sum(q);
    float rstd = rsqrtf(q*(1.f/512.f) + 1e-5f);
    #pragma unroll
    for (int i = 0; i < 8; i++){
        int c = lane + 64*i;
        out[b*512 + c] = (v[i]-mean)*rstd*g[c] + be[c];
    }
}

// ---------- bilinear upsample 4x4 -> 16x16 align_corners ----------
__global__ __launch_bounds__(256) void k_up(const float* __restrict__ s, float* __restrict__ out){
    const int idx = blockIdx.x*256 + threadIdx.x;       // b*512*256 + ch*256 + y*16 + x
    const int x = idx & 15, y = (idx >> 4) & 15, bc = idx >> 8;
    float px = (float)(x*3) / 15.0f, py = (float)(y*3) / 15.0f;
    int lx = (int)px, ly = (int)py;
    float wx = px - lx, wy = py - ly;
    int hx = min(lx+1, 3), hy = min(ly+1, 3);
    const float* p = s + (size_t)bc * 16;
    float v00 = p[ly*4+lx], v01 = p[ly*4+hx], v10 = p[hy*4+lx], v11 = p[hy*4+hx];
    float a0 = v00*(1.f-wy) + v10*wy;
    float a1 = v01*(1.f-wy) + v11*wy;
    out[idx] = a0*(1.f-wx) + a1*wx;
}

// ---------- conv1x1: out[b][o][n] = epi(sum_c W[o][c]*X[b][c][n]) ----------
// 64o x 32n tile, 128 threads, grid (8,8,8) = 512 blocks (2/CU), pipelined k-loop.
__global__ __launch_bounds__(128) void k_conv(
    const float* __restrict__ X, const float* __restrict__ W,
    const float* __restrict__ bias, const float* __restrict__ res,
    const float* __restrict__ bng, const float* __restrict__ bnb, float bninv,
    float* __restrict__ out, int flags)
{
    __shared__ float sW[16*64];
    __shared__ float sX[16*36];
    const int b = blockIdx.z, o0 = blockIdx.y*64, n0 = blockIdx.x*32;
    const int tid = threadIdx.x;
    const int tx = tid & 7, ty = tid >> 3;   // n = n0+tx*4+j, o = o0+ty*4+i
    const float* Xb = X + (size_t)b * IMG;
    const int lo  = tid >> 1;                // 0..63 (W row)
    const int lk8 = (tid & 1) * 8;           // 0 or 8 (k-offset)
    const int lkx = tid >> 3;                // 0..15 (X k-row)
    const int ln4 = (tid & 7) * 4;           // X n-offset
    const float* wrow = W + (size_t)(o0+lo)*512 + lk8;
    float4 wr0 = *(const float4*)(wrow);
    float4 wr1 = *(const float4*)(wrow + 4);
    float4 xr  = *(const float4*)(Xb + (size_t)lkx*256 + n0 + ln4);
    float acc[4][4] = {};
    for (int k0 = 0; k0 < 512; k0 += 16){
        __syncthreads();
        sW[(lk8+0)*64 + lo] = wr0.x; sW[(lk8+1)*64 + lo] = wr0.y;
        sW[(lk8+2)*64 + lo] = wr0.z; sW[(lk8+3)*64 + lo] = wr0.w;
        sW[(lk8+4)*64 + lo] = wr1.x; sW[(lk8+5)*64 + lo] = wr1.y;
        sW[(lk8+6)*64 + lo] = wr1.z; sW[(lk8+7)*64 + lo] = wr1.w;
        *(float4*)&sX[lkx*36 + ln4] = xr;
        __syncthreads();
        if (k0 + 16 < 512){   // prefetch next tile while computing this one
            wr0 = *(const float4*)(wrow + k0 + 16);
            wr1 = *(const float4*)(wrow + k0 + 20);
            xr  = *(const float4*)(Xb + (size_t)(k0+16+lkx)*256 + n0 + ln4);
        }
        #pragma unroll
        for (int k = 0; k < 16; k++){
            float4 av = *(const float4*)&sW[k*64 + ty*4];
            float4 bv = *(const float4*)&sX[k*36 + tx*4];
            float aa[4] = {av.x, av.y, av.z, av.w};
            float bb[4] = {bv.x, bv.y, bv.z, bv.w};
            #pragma unroll
            for (int i = 0; i < 4; i++)
                #pragma unroll
                for (int j = 0; j < 4; j++) acc[i][j] += aa[i]*bb[j];
        }
    }
    #pragma unroll
    for (int i = 0; i < 4; i++){
        const int o = o0 + ty*4 + i;
        const float bi = bias[o];
        float sc = 1.f, sh = 0.f;
        if (flags & CF_BN){ sc = bninv*bng[o]; sh = bnb[o]; }
        float t[4];
        #pragma unroll
        for (int j = 0; j < 4; j++){
            float v = acc[i][j] + bi;
            if (flags & CF_BN)   v = v*sc + sh;
            if (flags & CF_RELU) v = fmaxf(v, 0.f);
            t[j] = v;
        }
        size_t base = (size_t)b*IMG + (size_t)o*256 + n0 + tx*4;
        if (flags & CF_RES){
            float4 r4 = *(const float4*)(res + base);
            t[0]+=r4.x; t[1]+=r4.y; t[2]+=r4.z; t[3]+=r4.w;
        }
        *(float4*)(out + base) = make_float4(t[0], t[1], t[2], t[3]);
    }
}

// ---------- sscm attention weights [h][b][d] ----------
__global__ __launch_bounds__(64) void k_sscm_attn(const float* __restrict__ q8,
    const float* __restrict__ k8, float* __restrict__ attnw)
{
    const int h = blockIdx.x >> 3, b = blockIdx.x & 7, c = threadIdx.x;
    const int ci = c*8 + h;
    float qc = q8[b*512 + ci];
    float s[8];
    #pragma unroll
    for (int d = 0; d < 8; d++){
        float p = qc * k8[d*512 + ci];
        p = wave_sum(p);
        s[d] = p * 0.125f;
    }
    float m = s[0];
    #pragma unroll
    for (int d = 1; d < 8; d++) m = fmaxf(m, s[d]);
    float sum = 0.f;
    #pragma unroll
    for (int d = 0; d < 8; d++){ s[d] = __expf(s[d]-m); sum += s[d]; }
    float r = 1.f/sum;
    if (c < 8){
        float v = s[0];
        #pragma unroll
        for (int d = 1; d < 8; d++) if (c == d) v = s[d];
        attnw[blockIdx.x*8 + c] = v*r;
    }
}

// ---------- sscm apply: out[b][e][pix] = sum_d attnw[e%8][b][d] * v[d][e][pix] ----------
__global__ __launch_bounds__(256) void k_sscm_apply(const float* __restrict__ attnw,
    const float* __restrict__ v, float* __restrict__ out)
{
    const int idx = blockIdx.x*256 + threadIdx.x;
    const int pix = idx & 255, e = (idx >> 8) & 511, b = idx >> 17;
    const int h = e & 7;
    const float* aw = attnw + (h*8 + b)*8;
    float acc = 0.f;
    #pragma unroll
    for (int d = 0; d < 8; d++) acc += aw[d] * v[(size_t)d*IMG + (size_t)e*256 + pix];
    out[idx] = acc;
}

// ---------- pixel cross-batch attention v2 ----------
// block = (nt, b, h): 32 queries, all d. S in registers (4q x 8m / thread),
// softmax via shfl over the 32 e-lanes, P via LDS round-trip.
// Thread map: a = tid>>5 (q = a+8i), e = tid&31 (m = e+32j; c = e+32jc).
__global__ __launch_bounds__(256) void k_pixel_attn(
    const float* __restrict__ Q, const float* __restrict__ K,
    const float* __restrict__ V, float* __restrict__ O)
{
    __shared__ float sQ[32*68];      // [q][c], stride 68
    __shared__ float sKV[256*20];    // K: [m][c-chunk16] stride 20; reused as V: [c][m-chunk64] stride 68
    __shared__ float sP[32*68];      // [q][m-chunk64], stride 68
    const int nt = blockIdx.x, b = blockIdx.y, h = blockIdx.z;
    const int tid = threadIdx.x;
    const int a = tid >> 5, e = tid & 31;
    const int n0 = nt * 32;
    const size_t bQ = (size_t)b * IMG;

    // stage Q tile: sQ[q][c] = Q[b][(c*8+h)*256 + n0+q]
    #pragma unroll
    for (int r = 0; r < 8; r++){
        int c = (tid >> 5) + 8*r;
        int q = tid & 31;
        sQ[q*68 + c] = Q[bQ + (size_t)(c*8+h)*256 + n0 + q];
    }

    float O_[4][2] = {};
    for (int d = 0; d < 8; d++){
        const size_t bK = (size_t)d * IMG;
        float S[4][8] = {};
        // ---- QK^T: S[q][m] = sum_c Q[q][c] K[m][c], c staged in 16-chunks ----
        for (int cc = 0; cc < 4; cc++){
            __syncthreads();
            #pragma unroll
            for (int r = 0; r < 16; r++){
                sKV[tid*20 + r] = K[bK + (size_t)((cc*16+r)*8 + h)*256 + tid];
            }
            __syncthreads();
            #pragma unroll
            for (int c4 = 0; c4 < 16; c4 += 4){
                float4 qv[4], kv[8];
                #pragma unroll
                for (int i = 0; i < 4; i++)
                    qv[i] = *(const float4*)&sQ[(a+8*i)*68 + cc*16 + c4];
                #pragma unroll
                for (int j = 0; j < 8; j++)
                    kv[j] = *(const float4*)&sKV[(e+32*j)*20 + c4];
                #pragma unroll
                for (int i = 0; i < 4; i++){
                    #pragma unroll
                    for (int j = 0; j < 8; j++)
                        S[i][j] += qv[i].x*kv[j].x + qv[i].y*kv[j].y
                                 + qv[i].z*kv[j].z + qv[i].w*kv[j].w;
                }
            }
        }
        // ---- softmax over m (256) per query row; row lives on 32 e-lanes ----
        #pragma unroll
        for (int i = 0; i < 4; i++){
            float mx = S[i][0];
            #pragma unroll
            for (int j = 1; j < 8; j++) mx = fmaxf(mx, S[i][j]);
            mx = fmaxf(mx, __shfl_xor(mx, 1));
            mx = fmaxf(mx, __shfl_xor(mx, 2));
            mx = fmaxf(mx, __shfl_xor(mx, 4));
            mx = fmaxf(mx, __shfl_xor(mx, 8));
            mx = fmaxf(mx, __shfl_xor(mx, 16));
            float sum = 0.f;
            #pragma unroll
            for (int j = 0; j < 8; j++){ S[i][j] = __expf(S[i][j]-mx); sum += S[i][j]; }
            sum += __shfl_xor(sum, 1);
            sum += __shfl_xor(sum, 2);
            sum += __shfl_xor(sum, 4);
            sum += __shfl_xor(sum, 8);
            sum += __shfl_xor(sum, 16);
            float r = 1.f/sum;
            #pragma unroll
            for (int j = 0; j < 8; j++) S[i][j] *= r;
        }
        // ---- O += P @ V_d, m staged in 64-chunks ----
        for (int mt = 0; mt < 4; mt++){
            __syncthreads();
            #pragma unroll
            for (int i = 0; i < 4; i++){
                sP[(a+8*i)*68 + e]      = S[i][2*mt];
                sP[(a+8*i)*68 + e + 32] = S[i][2*mt+1];
            }
            #pragma unroll
            for (int r = 0; r < 16; r++){
                int fl = r*256 + tid;
                int c = fl >> 6, ml = fl & 63;
                sKV[c*68 + ml] = V[bK + (size_t)(c*8+h)*256 + mt*64 + ml];
            }
            __syncthreads();
            #pragma unroll 4
            for (int m4 = 0; m4 < 64; m4 += 4){
                float4 pv[4], vv[2];
                #pragma unroll
                for (int i = 0; i < 4; i++)
                    pv[i] = *(const float4*)&sP[(a+8*i)*68 + m4];
                #pragma unroll
                for (int jc = 0; jc < 2; jc++)
                    vv[jc] = *(const float4*)&sKV[(e+32*jc)*68 + m4];
                #pragma unroll
                for (int i = 0; i < 4; i++){
                    #pragma unroll
                    for (int jc = 0; jc < 2; jc++)
                        O_[i][jc] += pv[i].x*vv[jc].x + pv[i].y*vv[jc].y
                                   + pv[i].z*vv[jc].z + pv[i].w*vv[jc].w;
                }
            }
        }
    }
    #pragma unroll
    for (int i = 0; i < 4; i++){
        #pragma unroll
        for (int jc = 0; jc < 2; jc++){
            int q = a + 8*i, c = e + 32*jc;
            O[bQ + (size_t)(c*8+h)*256 + n0 + q] = O_[i][jc];
        }
    }
}

// ---------- LN over channels (strided), keeps [b][c][n] layout ----------
__global__ __launch_bounds__(64) void k_ln_pix(const float* __restrict__ in,
    const float* __restrict__ g, const float* __restrict__ be, float* __restrict__ out)
{
    const int bn = blockIdx.x;                 // b*256 + n
    const int b = bn >> 8, n = bn & 255;
    const int lane = threadIdx.x;
    const float* p = in + (size_t)b*IMG + n;
    float v[8]; float s = 0.f;
    #pragma unroll
    for (int i = 0; i < 8; i++){ v[i] = p[(size_t)(lane + 64*i)*256]; s += v[i]; }
    s = wave_sum(s);
    float mean = s * (1.f/512.f);
    float q = 0.f;
    #pragma unroll
    for (int i = 0; i < 8; i++){ float d = v[i]-mean; q += d*d; }
    q = wave_sum(q);
    float rstd = rsqrtf(q*(1.f/512.f) + 1e-5f);
    #pragma unroll
    for (int i = 0; i < 8; i++){
        int c = lane + 64*i;
        out[(size_t)b*IMG + (size_t)c*256 + n] = (v[i]-mean)*rstd*g[c] + be[c];
    }
}

// ---------- host orchestration ----------
extern "C" void kernel_launch(void* const* d_in, const int* in_sizes, int n_in,
                              void* d_out, int out_size, void* d_ws, size_t ws_size,
                              hipStream_t stream)
{
    const float* xs    = (const float*)d_in[0];
    const float* xq    = (const float*)d_in[1];
    const float* qkvw  = (const float*)d_in[2];  const float* qkvb = (const float*)d_in[3];
    const float* paw   = (const float*)d_in[4];  const float* pab  = (const float*)d_in[5];
    const float* ln1g  = (const float*)d_in[6];  const float* ln1b = (const float*)d_in[7];
    const float* f1w   = (const float*)d_in[8];  const float* f1b  = (const float*)d_in[9];
    const float* f2w   = (const float*)d_in[10]; const float* f2b  = (const float*)d_in[11];
    const float* ln2g  = (const float*)d_in[12]; const float* ln2b = (const float*)d_in[13];
    const float* c1w   = (const float*)d_in[14]; const float* c1b  = (const float*)d_in[15];
    const float* c2w   = (const float*)d_in[16]; const float* c2b  = (const float*)d_in[17];
    const float* bng   = (const float*)d_in[18]; const float* bnb  = (const float*)d_in[19];
    const float* caqw  = (const float*)d_in[20]; const float* caqb = (const float*)d_in[21];
    const float* cakw  = (const float*)d_in[22]; const float* cakb = (const float*)d_in[23];
    const float* cavw  = (const float*)d_in[24]; const float* cavb = (const float*)d_in[25];
    const float* capw  = (const float*)d_in[26]; const float* capb = (const float*)d_in[27];
    const float* pqw   = (const float*)d_in[28]; const float* pqb  = (const float*)d_in[29];
    const float* pkw   = (const float*)d_in[30]; const float* pkb  = (const float*)d_in[31];
    const float* pvw   = (const float*)d_in[32]; const float* pvb  = (const float*)d_in[33];
    const float* ppw   = (const float*)d_in[34]; const float* ppb  = (const float*)d_in[35];
    const float* plng  = (const float*)d_in[36]; const float* plnb = (const float*)d_in[37];
    const float* plinw = (const float*)d_in[38]; const float* plinb= (const float*)d_in[39];

    float* ws = (float*)d_ws;
    float* sa_s = ws;
    float* sa_q = ws + 1*(size_t)BIGF;
    float* ca_s = ws + 2*(size_t)BIGF;
    float* ca_q = ws + 3*(size_t)BIGF;
    float* tA   = ws + 4*(size_t)BIGF;
    float* tB   = ws + 5*(size_t)BIGF;
    float* tC   = ws + 6*(size_t)BIGF;
    float* tD   = ws + 7*(size_t)BIGF;
    float* tE   = ws + 8*(size_t)BIGF;
    float* sm   = ws + 9*(size_t)BIGF;
    float* gap  = sm;            // 4096
    float* qkv  = sm + 4096;     // 16384
    float* om   = sm + 20480;    // 4096
    float* aa   = sm + 24576;    // 4096
    float* hb   = sm + 28672;    // 4096
    float* a2   = sm + 32768;    // 4096
    float* lnb_ = sm + 36864;    // 4096
    float* s8   = sm + 40960;    // 65536
    float* attnw= sm + 106496;   // 512
    float* q8   = sm + 107008;   // 4096
    float* k8   = sm + 111104;   // 4096

    const float bninv = 1.0f / sqrtf(1.0f + 1e-5f);
    const dim3 cgrid(8, 8, 8);   // n-tiles(32) x o-tiles(64) x batch

    auto asri = [&](const float* x, float* out){
        k_gap<<<4096, 64, 0, stream>>>(x, gap);
        k_gemm8<<<2048, 64, 0, stream>>>(gap, qkvw, qkvb, nullptr, 0, 0, qkv, 2048, 0);
        k_asri_attn<<<64, 64, 0, stream>>>(qkv, om);
        k_gemm8<<<512, 64, 0, stream>>>(om, paw, pab, qkv, 1536, 2048, aa, 512, 0);
        k_ln8<<<8, 64, 0, stream>>>(aa, ln1g, ln1b, lnb_);
        k_gemm8<<<512, 64, 0, stream>>>(lnb_, f1w, f1b, nullptr, 0, 0, hb, 512, 1);
        k_gemm8<<<512, 64, 0, stream>>>(hb, f2w, f2b, aa, 0, 512, a2, 512, 0);
        k_ln8<<<8, 64, 0, stream>>>(a2, ln2g, ln2b, lnb_);
        k_gemm8<<<8192, 64, 0, stream>>>(lnb_, c1w, c1b, nullptr, 0, 0, s8, 8192, 0);
        k_up<<<4096, 256, 0, stream>>>(s8, tA);
        k_conv<<<cgrid, 128, 0, stream>>>(tA, c2w, c2b, x, bng, bnb, bninv, out,
                                          CF_BN | CF_RELU | CF_RES);
    };
    asri(xs, sa_s);
    asri(xq, sa_q);

    auto sscm = [&](const float* x1, const float* x2, float* out){
        k_gap<<<4096, 64, 0, stream>>>(x1, gap);
        k_gemm8<<<512, 64, 0, stream>>>(gap, caqw, caqb, nullptr, 0, 0, q8, 512, 0);
        k_gap<<<4096, 64, 0, stream>>>(x2, gap);
        k_gemm8<<<512, 64, 0, stream>>>(gap, cakw, cakb, nullptr, 0, 0, k8, 512, 0);
        k_sscm_attn<<<64, 64, 0, stream>>>(q8, k8, attnw);
        k_conv<<<cgrid, 128, 0, stream>>>(x2, cavw, cavb, nullptr, nullptr, nullptr, 1.f, tA, 0);
        k_sscm_apply<<<4096, 256, 0, stream>>>(attnw, tA, tB);
        k_conv<<<cgrid, 128, 0, stream>>>(tB, capw, capb, nullptr, nullptr, nullptr, 1.f, out, CF_RELU);
    };
    sscm(sa_s, sa_q, ca_s);
    sscm(sa_q, sa_s, ca_q);

    auto pixel = [&](const float* x1, const float* x2, float* out){
        k_conv<<<cgrid, 128, 0, stream>>>(x1, pqw, pqb, nullptr, nullptr, nullptr, 1.f, tA, 0);
        k_conv<<<cgrid, 128, 0, stream>>>(x2, pkw, pkb, nullptr, nullptr, nullptr, 1.f, tB, 0);
        k_conv<<<cgrid, 128, 0, stream>>>(x2, pvw, pvb, nullptr, nullptr, nullptr, 1.f, tC, 0);
        k_pixel_attn<<<dim3(8, 8, 8), 256, 0, stream>>>(tA, tB, tC, tD);
        k_conv<<<cgrid, 128, 0, stream>>>(tD, ppw, ppb, x1, nullptr, nullptr, 1.f, tE, CF_RES);
        k_ln_pix<<<2048, 64, 0, stream>>>(tE, plng, plnb, tA);
        k_conv<<<cgrid, 128, 0, stream>>>(tA, plinw, plinb, nullptr, nullptr, nullptr, 1.f, out, CF_RELU);
    };
    float* out0 = (float*)d_out;
    pixel(sa_s, ca_q, out0);
    pixel(sa_q, ca_s, out0 + (size_t)BIGF);

    (void)in_sizes; (void)n_in; (void)out_size; (void)ws_size;
}

// Round 4
// 1221.758 us; speedup vs baseline: 2.8011x; 1.0289x over previous
//
#include <hip/hip_runtime.h>
#include <cmath>

// ---------- constants ----------
#define IMG 131072        // 512*256 per batch image
#define BIGF 1048576      // 8*512*256

#define CF_RELU 1
#define CF_RES  2
#define CF_BN   4

__device__ __forceinline__ float wave_sum(float v){
    #pragma unroll
    for (int off = 32; off; off >>= 1) v += __shfl_xor(v, off);
    return v;
}

// ---------- GAP: mean over 256 spatial ----------
__global__ __launch_bounds__(64) void k_gap(const float* __restrict__ x, float* __restrict__ out){
    const int bc = blockIdx.x;           // b*512 + c
    const int lane = threadIdx.x;
    const float* p = x + (size_t)bc * 256;
    float s = p[lane] + p[lane + 64] + p[lane + 128] + p[lane + 192];
    s = wave_sum(s);
    if (lane == 0) out[bc] = s * (1.0f / 256.0f);
}

// ---------- tiny GEMM: out[8,O] = in[8,512] @ W[O,512]^T + bias (+add) ----------
__global__ __launch_bounds__(64) void k_gemm8(
    const float* __restrict__ in, const float* __restrict__ W,
    const float* __restrict__ bias, const float* __restrict__ add,
    int add_off, int add_stride, float* __restrict__ out, int O, int relu)
{
    const int o = blockIdx.x;
    const int lane = threadIdx.x;
    const float* wr = W + (size_t)o * 512;
    float acc[8] = {0,0,0,0,0,0,0,0};
    #pragma unroll
    for (int i = 0; i < 8; i++){
        float w = wr[lane + 64*i];
        #pragma unroll
        for (int b = 0; b < 8; b++) acc[b] += w * in[b*512 + lane + 64*i];
    }
    #pragma unroll
    for (int b = 0; b < 8; b++) acc[b] = wave_sum(acc[b]);
    if (lane < 8){
        float v = acc[0];
        #pragma unroll
        for (int b = 1; b < 8; b++) if (lane == b) v = acc[b];
        v += bias[o];
        if (add) v += add[lane*add_stride + add_off + o];
        if (relu) v = fmaxf(v, 0.f);
        out[(size_t)lane * O + o] = v;
    }
}

// ---------- asri batch-axis attention; writes merged o [8,512] ----------
__global__ __launch_bounds__(64) void k_asri_attn(const float* __restrict__ qkv, float* __restrict__ om){
    const int h = blockIdx.x >> 3, b = blockIdx.x & 7, c = threadIdx.x;
    const int ci = c*8 + h;
    float qc = qkv[b*2048 + ci];            // slice 0 = q
    float s[8];
    #pragma unroll
    for (int d = 0; d < 8; d++){
        float p = qc * qkv[d*2048 + 512 + ci];   // slice 1 = k
        p = wave_sum(p);
        s[d] = p * 0.125f;                       // SCALE = 64^-0.5
    }
    float m = s[0];
    #pragma unroll
    for (int d = 1; d < 8; d++) m = fmaxf(m, s[d]);
    float sum = 0.f;
    #pragma unroll
    for (int d = 0; d < 8; d++){ s[d] = __expf(s[d]-m); sum += s[d]; }
    float r = 1.f / sum;
    float oc = 0.f;
    #pragma unroll
    for (int d = 0; d < 8; d++) oc += s[d]*r * qkv[d*2048 + 1024 + ci];  // slice 2 = v
    om[b*512 + ci] = oc;
}

// ---------- LN over 512, 8 rows ----------
__global__ __launch_bounds__(64) void k_ln8(const float* __restrict__ in,
    const float* __restrict__ g, const float* __restrict__ be, float* __restrict__ out)
{
    const int b = blockIdx.x, lane = threadIdx.x;
    float v[8]; float s = 0.f;
    #pragma unroll
    for (int i = 0; i < 8; i++){ v[i] = in[b*512 + lane + 64*i]; s += v[i]; }
    s = wave_sum(s);
    float mean = s * (1.f/512.f);
    float q = 0.f;
    #pragma unroll
    for (int i = 0; i < 8; i++){ float d = v[i]-mean; q += d*d; }
    q = wave_sum(q);
    float rstd = rsqrtf(q*(1.f/512.f) + 1e-5f);
    #pragma unroll
    for (int i = 0; i < 8; i++){
        int c = lane + 64*i;
        out[b*512 + c] = (v[i]-mean)*rstd*g[c] + be[c];
    }
}

// ---------- bilinear upsample 4x4 -> 16x16 align_corners ----------
__global__ __launch_bounds__(256) void k_up(const float* __restrict__ s, float* __restrict__ out){
    const int idx = blockIdx.x*256 + threadIdx.x;       // b*512*256 + ch*256 + y*16 + x
    const int x = idx & 15, y = (idx >> 4) & 15, bc = idx >> 8;
    float px = (float)(x*3) / 15.0f, py = (float)(y*3) / 15.0f;
    int lx = (int)px, ly = (int)py;
    float wx = px - lx, wy = py - ly;
    int hx = min(lx+1, 3), hy = min(ly+1, 3);
    const float* p = s + (size_t)bc * 16;
    float v00 = p[ly*4+lx], v01 = p[ly*4+hx], v10 = p[hy*4+lx], v11 = p[hy*4+hx];
    float a0 = v00*(1.f-wy) + v10*wy;
    float a1 = v01*(1.f-wy) + v11*wy;
    out[idx] = a0*(1.f-wx) + a1*wx;
}

// ---------- zero fill ----------
__global__ __launch_bounds__(256) void k_zero(float* __restrict__ p){
    p[(size_t)blockIdx.x*256 + threadIdx.x] = 0.f;
}

// ---------- conv1x1 GEMM body: 64o x 32n tile, 128 threads, LDS double-buffered ----------
__device__ __forceinline__ void conv_body(
    const float* __restrict__ Xb, const float* __restrict__ W,
    const float* __restrict__ bias, const float* __restrict__ resb,
    const float* __restrict__ bng, const float* __restrict__ bnb, float bninv,
    float* __restrict__ outb, int flags, int o0, int n0,
    float* sW, float* sX)      // sW: 2*16*64, sX: 2*16*36
{
    const int tid = threadIdx.x;
    const int tx = tid & 7, ty = tid >> 3;   // n = n0+tx*4+j, o = o0+ty*4+i
    const int lo  = tid >> 1;                // 0..63 (W row)
    const int lk8 = (tid & 1) * 8;           // 0 or 8 (k-offset)
    const int lkx = tid >> 3;                // 0..15 (X k-row)
    const int ln4 = (tid & 7) * 4;           // X n-offset
    const float* wrow = W + (size_t)(o0+lo)*512 + lk8;
    float4 wr0 = *(const float4*)(wrow);
    float4 wr1 = *(const float4*)(wrow + 4);
    float4 xr  = *(const float4*)(Xb + (size_t)lkx*256 + n0 + ln4);
    sW[(lk8+0)*64 + lo] = wr0.x; sW[(lk8+1)*64 + lo] = wr0.y;
    sW[(lk8+2)*64 + lo] = wr0.z; sW[(lk8+3)*64 + lo] = wr0.w;
    sW[(lk8+4)*64 + lo] = wr1.x; sW[(lk8+5)*64 + lo] = wr1.y;
    sW[(lk8+6)*64 + lo] = wr1.z; sW[(lk8+7)*64 + lo] = wr1.w;
    *(float4*)&sX[lkx*36 + ln4] = xr;
    __syncthreads();
    float acc[4][4] = {};
    int p = 0;
    for (int k0 = 16; k0 <= 512; k0 += 16){
        const bool more = (k0 < 512);
        if (more){
            wr0 = *(const float4*)(wrow + k0);
            wr1 = *(const float4*)(wrow + k0 + 4);
            xr  = *(const float4*)(Xb + (size_t)(k0+lkx)*256 + n0 + ln4);
        }
        const float* cW = sW + p*(16*64);
        const float* cX = sX + p*(16*36);
        #pragma unroll
        for (int k = 0; k < 16; k++){
            float4 av = *(const float4*)&cW[k*64 + ty*4];
            float4 bv = *(const float4*)&cX[k*36 + tx*4];
            float aa[4] = {av.x, av.y, av.z, av.w};
            float bb[4] = {bv.x, bv.y, bv.z, bv.w};
            #pragma unroll
            for (int i = 0; i < 4; i++)
                #pragma unroll
                for (int j = 0; j < 4; j++) acc[i][j] += aa[i]*bb[j];
        }
        if (more){
            float* nW = sW + (p^1)*(16*64);
            float* nX = sX + (p^1)*(16*36);
            nW[(lk8+0)*64 + lo] = wr0.x; nW[(lk8+1)*64 + lo] = wr0.y;
            nW[(lk8+2)*64 + lo] = wr0.z; nW[(lk8+3)*64 + lo] = wr0.w;
            nW[(lk8+4)*64 + lo] = wr1.x; nW[(lk8+5)*64 + lo] = wr1.y;
            nW[(lk8+6)*64 + lo] = wr1.z; nW[(lk8+7)*64 + lo] = wr1.w;
            *(float4*)&nX[lkx*36 + ln4] = xr;
            __syncthreads();
            p ^= 1;
        }
    }
    #pragma unroll
    for (int i = 0; i < 4; i++){
        const int o = o0 + ty*4 + i;
        const float bi = bias[o];
        float sc = 1.f, sh = 0.f;
        if (flags & CF_BN){ sc = bninv*bng[o]; sh = bnb[o]; }
        float t[4];
        #pragma unroll
        for (int j = 0; j < 4; j++){
            float v = acc[i][j] + bi;
            if (flags & CF_BN)   v = v*sc + sh;
            if (flags & CF_RELU) v = fmaxf(v, 0.f);
            t[j] = v;
        }
        size_t base = (size_t)o*256 + n0 + tx*4;
        if (flags & CF_RES){
            float4 r4 = *(const float4*)(resb + base);
            t[0]+=r4.x; t[1]+=r4.y; t[2]+=r4.z; t[3]+=r4.w;
        }
        *(float4*)(outb + base) = make_float4(t[0], t[1], t[2], t[3]);
    }
}

__global__ __launch_bounds__(128) void k_conv(
    const float* __restrict__ X, const float* __restrict__ W,
    const float* __restrict__ bias, const float* __restrict__ res,
    const float* __restrict__ bng, const float* __restrict__ bnb, float bninv,
    float* __restrict__ out, int flags)
{
    __shared__ float sW[2*16*64];
    __shared__ float sX[2*16*36];
    const int b = blockIdx.z, o0 = blockIdx.y*64, n0 = blockIdx.x*32;
    conv_body(X + (size_t)b*IMG, W, bias, res ? res + (size_t)b*IMG : nullptr,
              bng, bnb, bninv, out + (size_t)b*IMG, flags, o0, n0, sW, sX);
}

// three independent convs (q/k/v projections) in one launch
struct Trio {
    const float *X0,*X1,*X2, *W0,*W1,*W2, *B0,*B1,*B2;
    float *O0,*O1,*O2;
};
__global__ __launch_bounds__(128) void k_conv_trio(Trio t)
{
    __shared__ float sW[2*16*64];
    __shared__ float sX[2*16*36];
    const int g = blockIdx.z >> 3, b = blockIdx.z & 7;
    const int o0 = blockIdx.y*64, n0 = blockIdx.x*32;
    const float* X = (g==0) ? t.X0 : (g==1) ? t.X1 : t.X2;
    const float* W = (g==0) ? t.W0 : (g==1) ? t.W1 : t.W2;
    const float* B = (g==0) ? t.B0 : (g==1) ? t.B1 : t.B2;
    float*       O = (g==0) ? t.O0 : (g==1) ? t.O1 : t.O2;
    conv_body(X + (size_t)b*IMG, W, B, nullptr, nullptr, nullptr, 1.f,
              O + (size_t)b*IMG, 0, o0, n0, sW, sX);
}

// ---------- sscm attention weights [h][b][d] ----------
__global__ __launch_bounds__(64) void k_sscm_attn(const float* __restrict__ q8,
    const float* __restrict__ k8, float* __restrict__ attnw)
{
    const int h = blockIdx.x >> 3, b = blockIdx.x & 7, c = threadIdx.x;
    const int ci = c*8 + h;
    float qc = q8[b*512 + ci];
    float s[8];
    #pragma unroll
    for (int d = 0; d < 8; d++){
        float p = qc * k8[d*512 + ci];
        p = wave_sum(p);
        s[d] = p * 0.125f;
    }
    float m = s[0];
    #pragma unroll
    for (int d = 1; d < 8; d++) m = fmaxf(m, s[d]);
    float sum = 0.f;
    #pragma unroll
    for (int d = 0; d < 8; d++){ s[d] = __expf(s[d]-m); sum += s[d]; }
    float r = 1.f/sum;
    if (c < 8){
        float v = s[0];
        #pragma unroll
        for (int d = 1; d < 8; d++) if (c == d) v = s[d];
        attnw[blockIdx.x*8 + c] = v*r;
    }
}

// ---------- sscm apply: out[b][e][pix] = sum_d attnw[e%8][b][d] * v[d][e][pix] ----------
__global__ __launch_bounds__(256) void k_sscm_apply(const float* __restrict__ attnw,
    const float* __restrict__ v, float* __restrict__ out)
{
    const int idx = blockIdx.x*256 + threadIdx.x;
    const int pix = idx & 255, e = (idx >> 8) & 511, b = idx >> 17;
    const int h = e & 7;
    const float* aw = attnw + (h*8 + b)*8;
    float acc = 0.f;
    #pragma unroll
    for (int d = 0; d < 8; d++) acc += aw[d] * v[(size_t)d*IMG + (size_t)e*256 + pix];
    out[idx] = acc;
}

// ---------- pixel cross-batch attention v3: d-parallel ----------
// block = (nt, d, b, h): 32 queries, ONE key batch d. S in registers (4q x 8m),
// softmax via shfl over the 32 e-lanes (softmax is per-d => blocks independent),
// O accumulated across d-blocks via native fp32 global atomics into pre-zeroed O.
// Thread map: a = tid>>5 (q = a+8i), e = tid&31 (m = e+32j; c = e+32jc).
__global__ __launch_bounds__(256) void k_pixel_attn(
    const float* __restrict__ Q, const float* __restrict__ K,
    const float* __restrict__ V, float* __restrict__ O)
{
    __shared__ float sQ[32*68];      // [q][c], stride 68
    __shared__ float sKV[256*20];    // K: [m][c-chunk16] stride 20; reused as V: [c][m-chunk64] stride 68
    __shared__ float sP[32*68];      // [q][m-chunk64], stride 68
    const int nt = blockIdx.x & 7, d = blockIdx.x >> 3, b = blockIdx.y, h = blockIdx.z;
    const int tid = threadIdx.x;
    const int a = tid >> 5, e = tid & 31;
    const int n0 = nt * 32;
    const size_t bQ = (size_t)b * IMG;
    const size_t bK = (size_t)d * IMG;

    // stage Q tile: sQ[q][c] = Q[b][(c*8+h)*256 + n0+q]
    #pragma unroll
    for (int r = 0; r < 8; r++){
        int c = (tid >> 5) + 8*r;
        int q = tid & 31;
        sQ[q*68 + c] = Q[bQ + (size_t)(c*8+h)*256 + n0 + q];
    }

    float S[4][8] = {};
    // ---- QK^T: S[q][m] = sum_c Q[q][c] K[m][c], c staged in 16-chunks ----
    for (int cc = 0; cc < 4; cc++){
        __syncthreads();
        #pragma unroll
        for (int r = 0; r < 16; r++){
            sKV[tid*20 + r] = K[bK + (size_t)((cc*16+r)*8 + h)*256 + tid];
        }
        __syncthreads();
        #pragma unroll
        for (int c4 = 0; c4 < 16; c4 += 4){
            float4 qv[4], kv[8];
            #pragma unroll
            for (int i = 0; i < 4; i++)
                qv[i] = *(const float4*)&sQ[(a+8*i)*68 + cc*16 + c4];
            #pragma unroll
            for (int j = 0; j < 8; j++)
                kv[j] = *(const float4*)&sKV[(e+32*j)*20 + c4];
            #pragma unroll
            for (int i = 0; i < 4; i++){
                #pragma unroll
                for (int j = 0; j < 8; j++)
                    S[i][j] += qv[i].x*kv[j].x + qv[i].y*kv[j].y
                             + qv[i].z*kv[j].z + qv[i].w*kv[j].w;
            }
        }
    }
    // ---- softmax over m (256) per query row; row lives on 32 e-lanes ----
    #pragma unroll
    for (int i = 0; i < 4; i++){
        float mx = S[i][0];
        #pragma unroll
        for (int j = 1; j < 8; j++) mx = fmaxf(mx, S[i][j]);
        mx = fmaxf(mx, __shfl_xor(mx, 1));
        mx = fmaxf(mx, __shfl_xor(mx, 2));
        mx = fmaxf(mx, __shfl_xor(mx, 4));
        mx = fmaxf(mx, __shfl_xor(mx, 8));
        mx = fmaxf(mx, __shfl_xor(mx, 16));
        float sum = 0.f;
        #pragma unroll
        for (int j = 0; j < 8; j++){ S[i][j] = __expf(S[i][j]-mx); sum += S[i][j]; }
        sum += __shfl_xor(sum, 1);
        sum += __shfl_xor(sum, 2);
        sum += __shfl_xor(sum, 4);
        sum += __shfl_xor(sum, 8);
        sum += __shfl_xor(sum, 16);
        float r = 1.f/sum;
        #pragma unroll
        for (int j = 0; j < 8; j++) S[i][j] *= r;
    }
    // ---- O_partial = P @ V_d, m staged in 64-chunks ----
    float O_[4][2] = {};
    for (int mt = 0; mt < 4; mt++){
        __syncthreads();
        #pragma unroll
        for (int i = 0; i < 4; i++){
            sP[(a+8*i)*68 + e]      = S[i][2*mt];
            sP[(a+8*i)*68 + e + 32] = S[i][2*mt+1];
        }
        #pragma unroll
        for (int r = 0; r < 16; r++){
            int fl = r*256 + tid;
            int c = fl >> 6, ml = fl & 63;
            sKV[c*68 + ml] = V[bK + (size_t)(c*8+h)*256 + mt*64 + ml];
        }
        __syncthreads();
        #pragma unroll 4
        for (int m4 = 0; m4 < 64; m4 += 4){
            float4 pv[4], vv[2];
            #pragma unroll
            for (int i = 0; i < 4; i++)
                pv[i] = *(const float4*)&sP[(a+8*i)*68 + m4];
            #pragma unroll
            for (int jc = 0; jc < 2; jc++)
                vv[jc] = *(const float4*)&sKV[(e+32*jc)*68 + m4];
            #pragma unroll
            for (int i = 0; i < 4; i++){
                #pragma unroll
                for (int jc = 0; jc < 2; jc++)
                    O_[i][jc] += pv[i].x*vv[jc].x + pv[i].y*vv[jc].y
                               + pv[i].z*vv[jc].z + pv[i].w*vv[jc].w;
            }
        }
    }
    #pragma unroll
    for (int i = 0; i < 4; i++){
        #pragma unroll
        for (int jc = 0; jc < 2; jc++){
            int q = a + 8*i, c = e + 32*jc;
            unsafeAtomicAdd(&O[bQ + (size_t)(c*8+h)*256 + n0 + q], O_[i][jc]);
        }
    }
}

// ---------- LN over channels (strided), keeps [b][c][n] layout ----------
__global__ __launch_bounds__(64) void k_ln_pix(const float* __restrict__ in,
    const float* __restrict__ g, const float* __restrict__ be, float* __restrict__ out)
{
    const int bn = blockIdx.x;                 // b*256 + n
    const int b = bn >> 8, n = bn & 255;
    const int lane = threadIdx.x;
    const float* p = in + (size_t)b*IMG + n;
    float v[8]; float s = 0.f;
    #pragma unroll
    for (int i = 0; i < 8; i++){ v[i] = p[(size_t)(lane + 64*i)*256]; s += v[i]; }
    s = wave_sum(s);
    float mean = s * (1.f/512.f);
    float q = 0.f;
    #pragma unroll
    for (int i = 0; i < 8; i++){ float d = v[i]-mean; q += d*d; }
    q = wave_sum(q);
    float rstd = rsqrtf(q*(1.f/512.f) + 1e-5f);
    #pragma unroll
    for (int i = 0; i < 8; i++){
        int c = lane + 64*i;
        out[(size_t)b*IMG + (size_t)c*256 + n] = (v[i]-mean)*rstd*g[c] + be[c];
    }
}

// ---------- host orchestration ----------
extern "C" void kernel_launch(void* const* d_in, const int* in_sizes, int n_in,
                              void* d_out, int out_size, void* d_ws, size_t ws_size,
                              hipStream_t stream)
{
    const float* xs    = (const float*)d_in[0];
    const float* xq    = (const float*)d_in[1];
    const float* qkvw  = (const float*)d_in[2];  const float* qkvb = (const float*)d_in[3];
    const float* paw   = (const float*)d_in[4];  const float* pab  = (const float*)d_in[5];
    const float* ln1g  = (const float*)d_in[6];  const float* ln1b = (const float*)d_in[7];
    const float* f1w   = (const float*)d_in[8];  const float* f1b  = (const float*)d_in[9];
    const float* f2w   = (const float*)d_in[10]; const float* f2b  = (const float*)d_in[11];
    const float* ln2g  = (const float*)d_in[12]; const float* ln2b = (const float*)d_in[13];
    const float* c1w   = (const float*)d_in[14]; const float* c1b  = (const float*)d_in[15];
    const float* c2w   = (const float*)d_in[16]; const float* c2b  = (const float*)d_in[17];
    const float* bng   = (const float*)d_in[18]; const float* bnb  = (const float*)d_in[19];
    const float* caqw  = (const float*)d_in[20]; const float* caqb = (const float*)d_in[21];
    const float* cakw  = (const float*)d_in[22]; const float* cakb = (const float*)d_in[23];
    const float* cavw  = (const float*)d_in[24]; const float* cavb = (const float*)d_in[25];
    const float* capw  = (const float*)d_in[26]; const float* capb = (const float*)d_in[27];
    const float* pqw   = (const float*)d_in[28]; const float* pqb  = (const float*)d_in[29];
    const float* pkw   = (const float*)d_in[30]; const float* pkb  = (const float*)d_in[31];
    const float* pvw   = (const float*)d_in[32]; const float* pvb  = (const float*)d_in[33];
    const float* ppw   = (const float*)d_in[34]; const float* ppb  = (const float*)d_in[35];
    const float* plng  = (const float*)d_in[36]; const float* plnb = (const float*)d_in[37];
    const float* plinw = (const float*)d_in[38]; const float* plinb= (const float*)d_in[39];

    float* ws = (float*)d_ws;
    float* sa_s = ws;
    float* sa_q = ws + 1*(size_t)BIGF;
    float* ca_s = ws + 2*(size_t)BIGF;
    float* ca_q = ws + 3*(size_t)BIGF;
    float* tA   = ws + 4*(size_t)BIGF;
    float* tB   = ws + 5*(size_t)BIGF;
    float* tC   = ws + 6*(size_t)BIGF;
    float* tD   = ws + 7*(size_t)BIGF;
    float* tE   = ws + 8*(size_t)BIGF;
    float* sm   = ws + 9*(size_t)BIGF;
    float* gap  = sm;            // 4096
    float* qkv  = sm + 4096;     // 16384
    float* om   = sm + 20480;    // 4096
    float* aa   = sm + 24576;    // 4096
    float* hb   = sm + 28672;    // 4096
    float* a2   = sm + 32768;    // 4096
    float* lnb_ = sm + 36864;    // 4096
    float* s8   = sm + 40960;    // 65536
    float* attnw= sm + 106496;   // 512
    float* q8   = sm + 107008;   // 4096
    float* k8   = sm + 111104;   // 4096

    const float bninv = 1.0f / sqrtf(1.0f + 1e-5f);
    const dim3 cgrid(8, 8, 8);   // n-tiles(32) x o-tiles(64) x batch

    auto asri = [&](const float* x, float* out){
        k_gap<<<4096, 64, 0, stream>>>(x, gap);
        k_gemm8<<<2048, 64, 0, stream>>>(gap, qkvw, qkvb, nullptr, 0, 0, qkv, 2048, 0);
        k_asri_attn<<<64, 64, 0, stream>>>(qkv, om);
        k_gemm8<<<512, 64, 0, stream>>>(om, paw, pab, qkv, 1536, 2048, aa, 512, 0);
        k_ln8<<<8, 64, 0, stream>>>(aa, ln1g, ln1b, lnb_);
        k_gemm8<<<512, 64, 0, stream>>>(lnb_, f1w, f1b, nullptr, 0, 0, hb, 512, 1);
        k_gemm8<<<512, 64, 0, stream>>>(hb, f2w, f2b, aa, 0, 512, a2, 512, 0);
        k_ln8<<<8, 64, 0, stream>>>(a2, ln2g, ln2b, lnb_);
        k_gemm8<<<8192, 64, 0, stream>>>(lnb_, c1w, c1b, nullptr, 0, 0, s8, 8192, 0);
        k_up<<<4096, 256, 0, stream>>>(s8, tA);
        k_conv<<<cgrid, 128, 0, stream>>>(tA, c2w, c2b, x, bng, bnb, bninv, out,
                                          CF_BN | CF_RELU | CF_RES);
    };
    asri(xs, sa_s);
    asri(xq, sa_q);

    auto sscm = [&](const float* x1, const float* x2, float* out){
        k_gap<<<4096, 64, 0, stream>>>(x1, gap);
        k_gemm8<<<512, 64, 0, stream>>>(gap, caqw, caqb, nullptr, 0, 0, q8, 512, 0);
        k_gap<<<4096, 64, 0, stream>>>(x2, gap);
        k_gemm8<<<512, 64, 0, stream>>>(gap, cakw, cakb, nullptr, 0, 0, k8, 512, 0);
        k_sscm_attn<<<64, 64, 0, stream>>>(q8, k8, attnw);
        k_conv<<<cgrid, 128, 0, stream>>>(x2, cavw, cavb, nullptr, nullptr, nullptr, 1.f, tA, 0);
        k_sscm_apply<<<4096, 256, 0, stream>>>(attnw, tA, tB);
        k_conv<<<cgrid, 128, 0, stream>>>(tB, capw, capb, nullptr, nullptr, nullptr, 1.f, out, CF_RELU);
    };
    sscm(sa_s, sa_q, ca_s);
    sscm(sa_q, sa_s, ca_q);

    auto pixel = [&](const float* x1, const float* x2, float* out){
        Trio t;
        t.X0 = x1; t.W0 = pqw; t.B0 = pqb; t.O0 = tA;
        t.X1 = x2; t.W1 = pkw; t.B1 = pkb; t.O1 = tB;
        t.X2 = x2; t.W2 = pvw; t.B2 = pvb; t.O2 = tC;
        k_conv_trio<<<dim3(8, 8, 24), 128, 0, stream>>>(t);
        k_zero<<<4096, 256, 0, stream>>>(tD);
        k_pixel_attn<<<dim3(64, 8, 8), 256, 0, stream>>>(tA, tB, tC, tD);
        k_conv<<<cgrid, 128, 0, stream>>>(tD, ppw, ppb, x1, nullptr, nullptr, 1.f, tE, CF_RES);
        k_ln_pix<<<2048, 64, 0, stream>>>(tE, plng, plnb, tA);
        k_conv<<<cgrid, 128, 0, stream>>>(tA, plinw, plinb, nullptr, nullptr, nullptr, 1.f, out, CF_RELU);
    };
    float* out0 = (float*)d_out;
    pixel(sa_s, ca_q, out0);
    pixel(sa_q, ca_s, out0 + (size_t)BIGF);

    (void)in_sizes; (void)n_in; (void)out_size; (void)ws_size;
}

// Round 5
// 1104.113 us; speedup vs baseline: 3.0995x; 1.1066x over previous
//
#include <hip/hip_runtime.h>
#include <cmath>

// ---------- constants ----------
#define IMG 131072        // 512*256 per batch image
#define BIGF 1048576      // 8*512*256

#define CF_RELU 1
#define CF_RES  2
#define CF_BN   4

typedef __attribute__((ext_vector_type(8))) short short8;
typedef __attribute__((ext_vector_type(4))) float f32x4;

__device__ __forceinline__ float wave_sum(float v){
    #pragma unroll
    for (int off = 32; off; off >>= 1) v += __shfl_xor(v, off);
    return v;
}

__device__ __forceinline__ unsigned short bf16_rn(float x){
    union { float f; unsigned u; } v; v.f = x;
    unsigned r = v.u + 0x7FFF + ((v.u >> 16) & 1);
    return (unsigned short)(r >> 16);
}
__device__ __forceinline__ float bf16_to_f(unsigned short h){
    union { float f; unsigned u; } v; v.u = ((unsigned)h) << 16;
    return v.f;
}

// ---------- GAP: mean over 256 spatial ----------
__global__ __launch_bounds__(64) void k_gap(const float* __restrict__ x, float* __restrict__ out){
    const int bc = blockIdx.x;           // b*512 + c
    const int lane = threadIdx.x;
    const float* p = x + (size_t)bc * 256;
    float s = p[lane] + p[lane + 64] + p[lane + 128] + p[lane + 192];
    s = wave_sum(s);
    if (lane == 0) out[bc] = s * (1.0f / 256.0f);
}

// ---------- tiny GEMM: out[8,O] = in[8,512] @ W[O,512]^T + bias (+add) ----------
__global__ __launch_bounds__(64) void k_gemm8(
    const float* __restrict__ in, const float* __restrict__ W,
    const float* __restrict__ bias, const float* __restrict__ add,
    int add_off, int add_stride, float* __restrict__ out, int O, int relu)
{
    const int o = blockIdx.x;
    const int lane = threadIdx.x;
    const float* wr = W + (size_t)o * 512;
    float acc[8] = {0,0,0,0,0,0,0,0};
    #pragma unroll
    for (int i = 0; i < 8; i++){
        float w = wr[lane + 64*i];
        #pragma unroll
        for (int b = 0; b < 8; b++) acc[b] += w * in[b*512 + lane + 64*i];
    }
    #pragma unroll
    for (int b = 0; b < 8; b++) acc[b] = wave_sum(acc[b]);
    if (lane < 8){
        float v = acc[0];
        #pragma unroll
        for (int b = 1; b < 8; b++) if (lane == b) v = acc[b];
        v += bias[o];
        if (add) v += add[lane*add_stride + add_off + o];
        if (relu) v = fmaxf(v, 0.f);
        out[(size_t)lane * O + o] = v;
    }
}

// ---------- asri batch-axis attention; writes merged o [8,512] ----------
__global__ __launch_bounds__(64) void k_asri_attn(const float* __restrict__ qkv, float* __restrict__ om){
    const int h = blockIdx.x >> 3, b = blockIdx.x & 7, c = threadIdx.x;
    const int ci = c*8 + h;
    float qc = qkv[b*2048 + ci];            // slice 0 = q
    float s[8];
    #pragma unroll
    for (int d = 0; d < 8; d++){
        float p = qc * qkv[d*2048 + 512 + ci];   // slice 1 = k
        p = wave_sum(p);
        s[d] = p * 0.125f;                       // SCALE = 64^-0.5
    }
    float m = s[0];
    #pragma unroll
    for (int d = 1; d < 8; d++) m = fmaxf(m, s[d]);
    float sum = 0.f;
    #pragma unroll
    for (int d = 0; d < 8; d++){ s[d] = __expf(s[d]-m); sum += s[d]; }
    float r = 1.f / sum;
    float oc = 0.f;
    #pragma unroll
    for (int d = 0; d < 8; d++) oc += s[d]*r * qkv[d*2048 + 1024 + ci];  // slice 2 = v
    om[b*512 + ci] = oc;
}

// ---------- LN over 512, 8 rows ----------
__global__ __launch_bounds__(64) void k_ln8(const float* __restrict__ in,
    const float* __restrict__ g, const float* __restrict__ be, float* __restrict__ out)
{
    const int b = blockIdx.x, lane = threadIdx.x;
    float v[8]; float s = 0.f;
    #pragma unroll
    for (int i = 0; i < 8; i++){ v[i] = in[b*512 + lane + 64*i]; s += v[i]; }
    s = wave_sum(s);
    float mean = s * (1.f/512.f);
    float q = 0.f;
    #pragma unroll
    for (int i = 0; i < 8; i++){ float d = v[i]-mean; q += d*d; }
    q = wave_sum(q);
    float rstd = rsqrtf(q*(1.f/512.f) + 1e-5f);
    #pragma unroll
    for (int i = 0; i < 8; i++){
        int c = lane + 64*i;
        out[b*512 + c] = (v[i]-mean)*rstd*g[c] + be[c];
    }
}

// ---------- bilinear upsample 4x4 -> 16x16 align_corners ----------
__global__ __launch_bounds__(256) void k_up(const float* __restrict__ s, float* __restrict__ out){
    const int idx = blockIdx.x*256 + threadIdx.x;       // b*512*256 + ch*256 + y*16 + x
    const int x = idx & 15, y = (idx >> 4) & 15, bc = idx >> 8;
    float px = (float)(x*3) / 15.0f, py = (float)(y*3) / 15.0f;
    int lx = (int)px, ly = (int)py;
    float wx = px - lx, wy = py - ly;
    int hx = min(lx+1, 3), hy = min(ly+1, 3);
    const float* p = s + (size_t)bc * 16;
    float v00 = p[ly*4+lx], v01 = p[ly*4+hx], v10 = p[hy*4+lx], v11 = p[hy*4+hx];
    float a0 = v00*(1.f-wy) + v10*wy;
    float a1 = v01*(1.f-wy) + v11*wy;
    out[idx] = a0*(1.f-wx) + a1*wx;
}

// ---------- zero fill ----------
__global__ __launch_bounds__(256) void k_zero(float* __restrict__ p){
    p[(size_t)blockIdx.x*256 + threadIdx.x] = 0.f;
}

// ---------- conv1x1 via split-bf16 MFMA ----------
// out[b][o][n] = epi(sum_c W[o][c] X[b][c][n]);  W,X fp32 -> (hi,lo) bf16,
// W*X = Wh*Xh + Wh*Xl + Wl*Xh  (3 chained mfma_f32_16x16x32_bf16, fp32 acc).
// Block 256 thr = 4 waves; tile 64o x 64n; wave = 32o x 32n (2x2 MFMA tiles).
// LDS rows padded to 40 bf16 so frag ds_read_b128 are <=2-way (free).
#define LDK 40
__device__ __forceinline__ void convm_body(
    const float* __restrict__ Xb, const float* __restrict__ W,
    const float* __restrict__ bias, const float* __restrict__ resb,
    const float* __restrict__ bng, const float* __restrict__ bnb, float bninv,
    float* __restrict__ outb, int flags, int o0, int n0,
    unsigned short* sAh, unsigned short* sAl,
    unsigned short* sBh, unsigned short* sBl)
{
    const int tid  = threadIdx.x;
    const int wv   = tid >> 6, lane = tid & 63;
    const int quad = lane >> 4, l16 = lane & 15;
    const int wo = (wv >> 1) * 32, wn = (wv & 1) * 32;
    // staging: W rows (so = tid>>2, k-offset sk8 = (tid&3)*8)
    const int so  = tid >> 2;
    const int sk8 = (tid & 3) * 8;
    // staging: X k-pair sp = tid&15 (k = 2sp,2sp+1), n-offset sn = (tid>>4)*4
    const int sp  = tid & 15;
    const int sn  = (tid >> 4) * 4;

    const float* wrow = W + (size_t)(o0 + so)*512 + sk8;
    const float* xrow = Xb + (size_t)(2*sp)*256 + n0 + sn;

    f32x4 acc[2][2] = {};
    float4 a0 = *(const float4*)(wrow);
    float4 a1 = *(const float4*)(wrow + 4);
    float4 x0 = *(const float4*)(xrow);
    float4 x1 = *(const float4*)(xrow + 256);

    for (int k0 = 0; k0 < 512; k0 += 32){
        __syncthreads();
        {   // pack W pairs (k,k+1) -> b32 into hi/lo planes
            float wa[8] = {a0.x,a0.y,a0.z,a0.w,a1.x,a1.y,a1.z,a1.w};
            #pragma unroll
            for (int j = 0; j < 4; j++){
                unsigned short h0 = bf16_rn(wa[2*j]);
                unsigned short h1 = bf16_rn(wa[2*j+1]);
                unsigned short g0 = bf16_rn(wa[2*j]   - bf16_to_f(h0));
                unsigned short g1 = bf16_rn(wa[2*j+1] - bf16_to_f(h1));
                *(unsigned*)&sAh[so*LDK + sk8 + 2*j] = (unsigned)h0 | ((unsigned)h1 << 16);
                *(unsigned*)&sAl[so*LDK + sk8 + 2*j] = (unsigned)g0 | ((unsigned)g1 << 16);
            }
            // pack X^T pairs: for n = sn+j, (k=2sp, 2sp+1)
            float xe[4] = {x0.x,x0.y,x0.z,x0.w};
            float xo[4] = {x1.x,x1.y,x1.z,x1.w};
            #pragma unroll
            for (int j = 0; j < 4; j++){
                unsigned short h0 = bf16_rn(xe[j]);
                unsigned short h1 = bf16_rn(xo[j]);
                unsigned short g0 = bf16_rn(xe[j] - bf16_to_f(h0));
                unsigned short g1 = bf16_rn(xo[j] - bf16_to_f(h1));
                *(unsigned*)&sBh[(sn+j)*LDK + 2*sp] = (unsigned)h0 | ((unsigned)h1 << 16);
                *(unsigned*)&sBl[(sn+j)*LDK + 2*sp] = (unsigned)g0 | ((unsigned)g1 << 16);
            }
        }
        __syncthreads();
        if (k0 + 32 < 512){   // prefetch next tile
            a0 = *(const float4*)(wrow + k0 + 32);
            a1 = *(const float4*)(wrow + k0 + 36);
            x0 = *(const float4*)(xrow + (size_t)(k0+32)*256);
            x1 = *(const float4*)(xrow + (size_t)(k0+32)*256 + 256);
        }
        short8 ah[2], al[2], bh[2], bl[2];
        #pragma unroll
        for (int t = 0; t < 2; t++){
            int ai = (wo + 16*t + l16)*LDK + quad*8;
            ah[t] = *(const short8*)&sAh[ai];
            al[t] = *(const short8*)&sAl[ai];
            int bi = (wn + 16*t + l16)*LDK + quad*8;
            bh[t] = *(const short8*)&sBh[bi];
            bl[t] = *(const short8*)&sBl[bi];
        }
        #pragma unroll
        for (int mt = 0; mt < 2; mt++){
            #pragma unroll
            for (int nt = 0; nt < 2; nt++){
                acc[mt][nt] = __builtin_amdgcn_mfma_f32_16x16x32_bf16(ah[mt], bh[nt], acc[mt][nt], 0, 0, 0);
                acc[mt][nt] = __builtin_amdgcn_mfma_f32_16x16x32_bf16(ah[mt], bl[nt], acc[mt][nt], 0, 0, 0);
                acc[mt][nt] = __builtin_amdgcn_mfma_f32_16x16x32_bf16(al[mt], bh[nt], acc[mt][nt], 0, 0, 0);
            }
        }
    }
    // epilogue: C/D layout col(n)=lane&15, row(o)=quad*4+reg  [measured m89]
    #pragma unroll
    for (int mt = 0; mt < 2; mt++){
        #pragma unroll
        for (int nt = 0; nt < 2; nt++){
            const int n  = n0 + wn + 16*nt + l16;
            const int ob = o0 + wo + 16*mt + quad*4;
            #pragma unroll
            for (int r = 0; r < 4; r++){
                const int o = ob + r;
                float v = acc[mt][nt][r] + bias[o];
                if (flags & CF_BN)   v = v*(bninv*bng[o]) + bnb[o];
                if (flags & CF_RELU) v = fmaxf(v, 0.f);
                if (flags & CF_RES)  v += resb[(size_t)o*256 + n];
                outb[(size_t)o*256 + n] = v;
            }
        }
    }
}

__global__ __launch_bounds__(256) void k_convm(
    const float* __restrict__ X, const float* __restrict__ W,
    const float* __restrict__ bias, const float* __restrict__ res,
    const float* __restrict__ bng, const float* __restrict__ bnb, float bninv,
    float* __restrict__ out, int flags)
{
    __shared__ unsigned short sAh[64*LDK], sAl[64*LDK], sBh[64*LDK], sBl[64*LDK];
    const int b = blockIdx.z, o0 = blockIdx.y*64, n0 = blockIdx.x*64;
    convm_body(X + (size_t)b*IMG, W, bias, res ? res + (size_t)b*IMG : nullptr,
               bng, bnb, bninv, out + (size_t)b*IMG, flags, o0, n0,
               sAh, sAl, sBh, sBl);
}

// three independent convs (q/k/v projections) in one launch
struct Trio {
    const float *X0,*X1,*X2, *W0,*W1,*W2, *B0,*B1,*B2;
    float *O0,*O1,*O2;
};
__global__ __launch_bounds__(256) void k_convm_trio(Trio t)
{
    __shared__ unsigned short sAh[64*LDK], sAl[64*LDK], sBh[64*LDK], sBl[64*LDK];
    const int g = blockIdx.z >> 3, b = blockIdx.z & 7;
    const int o0 = blockIdx.y*64, n0 = blockIdx.x*64;
    const float* X = (g==0) ? t.X0 : (g==1) ? t.X1 : t.X2;
    const float* W = (g==0) ? t.W0 : (g==1) ? t.W1 : t.W2;
    const float* B = (g==0) ? t.B0 : (g==1) ? t.B1 : t.B2;
    float*       O = (g==0) ? t.O0 : (g==1) ? t.O1 : t.O2;
    convm_body(X + (size_t)b*IMG, W, B, nullptr, nullptr, nullptr, 1.f,
               O + (size_t)b*IMG, 0, o0, n0, sAh, sAl, sBh, sBl);
}

// ---------- sscm attention weights [h][b][d] ----------
__global__ __launch_bounds__(64) void k_sscm_attn(const float* __restrict__ q8,
    const float* __restrict__ k8, float* __restrict__ attnw)
{
    const int h = blockIdx.x >> 3, b = blockIdx.x & 7, c = threadIdx.x;
    const int ci = c*8 + h;
    float qc = q8[b*512 + ci];
    float s[8];
    #pragma unroll
    for (int d = 0; d < 8; d++){
        float p = qc * k8[d*512 + ci];
        p = wave_sum(p);
        s[d] = p * 0.125f;
    }
    float m = s[0];
    #pragma unroll
    for (int d = 1; d < 8; d++) m = fmaxf(m, s[d]);
    float sum = 0.f;
    #pragma unroll
    for (int d = 0; d < 8; d++){ s[d] = __expf(s[d]-m); sum += s[d]; }
    float r = 1.f/sum;
    if (c < 8){
        float v = s[0];
        #pragma unroll
        for (int d = 1; d < 8; d++) if (c == d) v = s[d];
        attnw[blockIdx.x*8 + c] = v*r;
    }
}

// ---------- sscm apply: out[b][e][pix] = sum_d attnw[e%8][b][d] * v[d][e][pix] ----------
__global__ __launch_bounds__(256) void k_sscm_apply(const float* __restrict__ attnw,
    const float* __restrict__ v, float* __restrict__ out)
{
    const int idx = blockIdx.x*256 + threadIdx.x;
    const int pix = idx & 255, e = (idx >> 8) & 511, b = idx >> 17;
    const int h = e & 7;
    const float* aw = attnw + (h*8 + b)*8;
    float acc = 0.f;
    #pragma unroll
    for (int d = 0; d < 8; d++) acc += aw[d] * v[(size_t)d*IMG + (size_t)e*256 + pix];
    out[idx] = acc;
}

// ---------- pixel cross-batch attention (d-parallel, LDS-BW bound ~288us) ----------
__global__ __launch_bounds__(256) void k_pixel_attn(
    const float* __restrict__ Q, const float* __restrict__ K,
    const float* __restrict__ V, float* __restrict__ O)
{
    __shared__ float sQ[32*68];      // [q][c], stride 68
    __shared__ float sKV[256*20];    // K: [m][c-chunk16] stride 20; reused as V: [c][m-chunk64] stride 68
    __shared__ float sP[32*68];      // [q][m-chunk64], stride 68
    const int nt = blockIdx.x & 7, d = blockIdx.x >> 3, b = blockIdx.y, h = blockIdx.z;
    const int tid = threadIdx.x;
    const int a = tid >> 5, e = tid & 31;
    const int n0 = nt * 32;
    const size_t bQ = (size_t)b * IMG;
    const size_t bK = (size_t)d * IMG;

    #pragma unroll
    for (int r = 0; r < 8; r++){
        int c = (tid >> 5) + 8*r;
        int q = tid & 31;
        sQ[q*68 + c] = Q[bQ + (size_t)(c*8+h)*256 + n0 + q];
    }

    float S[4][8] = {};
    for (int cc = 0; cc < 4; cc++){
        __syncthreads();
        #pragma unroll
        for (int r = 0; r < 16; r++){
            sKV[tid*20 + r] = K[bK + (size_t)((cc*16+r)*8 + h)*256 + tid];
        }
        __syncthreads();
        #pragma unroll
        for (int c4 = 0; c4 < 16; c4 += 4){
            float4 qv[4], kv[8];
            #pragma unroll
            for (int i = 0; i < 4; i++)
                qv[i] = *(const float4*)&sQ[(a+8*i)*68 + cc*16 + c4];
            #pragma unroll
            for (int j = 0; j < 8; j++)
                kv[j] = *(const float4*)&sKV[(e+32*j)*20 + c4];
            #pragma unroll
            for (int i = 0; i < 4; i++){
                #pragma unroll
                for (int j = 0; j < 8; j++)
                    S[i][j] += qv[i].x*kv[j].x + qv[i].y*kv[j].y
                             + qv[i].z*kv[j].z + qv[i].w*kv[j].w;
            }
        }
    }
    #pragma unroll
    for (int i = 0; i < 4; i++){
        float mx = S[i][0];
        #pragma unroll
        for (int j = 1; j < 8; j++) mx = fmaxf(mx, S[i][j]);
        mx = fmaxf(mx, __shfl_xor(mx, 1));
        mx = fmaxf(mx, __shfl_xor(mx, 2));
        mx = fmaxf(mx, __shfl_xor(mx, 4));
        mx = fmaxf(mx, __shfl_xor(mx, 8));
        mx = fmaxf(mx, __shfl_xor(mx, 16));
        float sum = 0.f;
        #pragma unroll
        for (int j = 0; j < 8; j++){ S[i][j] = __expf(S[i][j]-mx); sum += S[i][j]; }
        sum += __shfl_xor(sum, 1);
        sum += __shfl_xor(sum, 2);
        sum += __shfl_xor(sum, 4);
        sum += __shfl_xor(sum, 8);
        sum += __shfl_xor(sum, 16);
        float r = 1.f/sum;
        #pragma unroll
        for (int j = 0; j < 8; j++) S[i][j] *= r;
    }
    float O_[4][2] = {};
    for (int mt = 0; mt < 4; mt++){
        __syncthreads();
        #pragma unroll
        for (int i = 0; i < 4; i++){
            sP[(a+8*i)*68 + e]      = S[i][2*mt];
            sP[(a+8*i)*68 + e + 32] = S[i][2*mt+1];
        }
        #pragma unroll
        for (int r = 0; r < 16; r++){
            int fl = r*256 + tid;
            int c = fl >> 6, ml = fl & 63;
            sKV[c*68 + ml] = V[bK + (size_t)(c*8+h)*256 + mt*64 + ml];
        }
        __syncthreads();
        #pragma unroll 4
        for (int m4 = 0; m4 < 64; m4 += 4){
            float4 pv[4], vv[2];
            #pragma unroll
            for (int i = 0; i < 4; i++)
                pv[i] = *(const float4*)&sP[(a+8*i)*68 + m4];
            #pragma unroll
            for (int jc = 0; jc < 2; jc++)
                vv[jc] = *(const float4*)&sKV[(e+32*jc)*68 + m4];
            #pragma unroll
            for (int i = 0; i < 4; i++){
                #pragma unroll
                for (int jc = 0; jc < 2; jc++)
                    O_[i][jc] += pv[i].x*vv[jc].x + pv[i].y*vv[jc].y
                               + pv[i].z*vv[jc].z + pv[i].w*vv[jc].w;
            }
        }
    }
    #pragma unroll
    for (int i = 0; i < 4; i++){
        #pragma unroll
        for (int jc = 0; jc < 2; jc++){
            int q = a + 8*i, c = e + 32*jc;
            unsafeAtomicAdd(&O[bQ + (size_t)(c*8+h)*256 + n0 + q], O_[i][jc]);
        }
    }
}

// ---------- LN over channels (strided), keeps [b][c][n] layout ----------
__global__ __launch_bounds__(64) void k_ln_pix(const float* __restrict__ in,
    const float* __restrict__ g, const float* __restrict__ be, float* __restrict__ out)
{
    const int bn = blockIdx.x;                 // b*256 + n
    const int b = bn >> 8, n = bn & 255;
    const int lane = threadIdx.x;
    const float* p = in + (size_t)b*IMG + n;
    float v[8]; float s = 0.f;
    #pragma unroll
    for (int i = 0; i < 8; i++){ v[i] = p[(size_t)(lane + 64*i)*256]; s += v[i]; }
    s = wave_sum(s);
    float mean = s * (1.f/512.f);
    float q = 0.f;
    #pragma unroll
    for (int i = 0; i < 8; i++){ float d = v[i]-mean; q += d*d; }
    q = wave_sum(q);
    float rstd = rsqrtf(q*(1.f/512.f) + 1e-5f);
    #pragma unroll
    for (int i = 0; i < 8; i++){
        int c = lane + 64*i;
        out[(size_t)b*IMG + (size_t)c*256 + n] = (v[i]-mean)*rstd*g[c] + be[c];
    }
}

// ---------- host orchestration ----------
extern "C" void kernel_launch(void* const* d_in, const int* in_sizes, int n_in,
                              void* d_out, int out_size, void* d_ws, size_t ws_size,
                              hipStream_t stream)
{
    const float* xs    = (const float*)d_in[0];
    const float* xq    = (const float*)d_in[1];
    const float* qkvw  = (const float*)d_in[2];  const float* qkvb = (const float*)d_in[3];
    const float* paw   = (const float*)d_in[4];  const float* pab  = (const float*)d_in[5];
    const float* ln1g  = (const float*)d_in[6];  const float* ln1b = (const float*)d_in[7];
    const float* f1w   = (const float*)d_in[8];  const float* f1b  = (const float*)d_in[9];
    const float* f2w   = (const float*)d_in[10]; const float* f2b  = (const float*)d_in[11];
    const float* ln2g  = (const float*)d_in[12]; const float* ln2b = (const float*)d_in[13];
    const float* c1w   = (const float*)d_in[14]; const float* c1b  = (const float*)d_in[15];
    const float* c2w   = (const float*)d_in[16]; const float* c2b  = (const float*)d_in[17];
    const float* bng   = (const float*)d_in[18]; const float* bnb  = (const float*)d_in[19];
    const float* caqw  = (const float*)d_in[20]; const float* caqb = (const float*)d_in[21];
    const float* cakw  = (const float*)d_in[22]; const float* cakb = (const float*)d_in[23];
    const float* cavw  = (const float*)d_in[24]; const float* cavb = (const float*)d_in[25];
    const float* capw  = (const float*)d_in[26]; const float* capb = (const float*)d_in[27];
    const float* pqw   = (const float*)d_in[28]; const float* pqb  = (const float*)d_in[29];
    const float* pkw   = (const float*)d_in[30]; const float* pkb  = (const float*)d_in[31];
    const float* pvw   = (const float*)d_in[32]; const float* pvb  = (const float*)d_in[33];
    const float* ppw   = (const float*)d_in[34]; const float* ppb  = (const float*)d_in[35];
    const float* plng  = (const float*)d_in[36]; const float* plnb = (const float*)d_in[37];
    const float* plinw = (const float*)d_in[38]; const float* plinb= (const float*)d_in[39];

    float* ws = (float*)d_ws;
    float* sa_s = ws;
    float* sa_q = ws + 1*(size_t)BIGF;
    float* ca_s = ws + 2*(size_t)BIGF;
    float* ca_q = ws + 3*(size_t)BIGF;
    float* tA   = ws + 4*(size_t)BIGF;
    float* tB   = ws + 5*(size_t)BIGF;
    float* tC   = ws + 6*(size_t)BIGF;
    float* tD   = ws + 7*(size_t)BIGF;
    float* tE   = ws + 8*(size_t)BIGF;
    float* sm   = ws + 9*(size_t)BIGF;
    float* gap  = sm;            // 4096
    float* qkv  = sm + 4096;     // 16384
    float* om   = sm + 20480;    // 4096
    float* aa   = sm + 24576;    // 4096
    float* hb   = sm + 28672;    // 4096
    float* a2   = sm + 32768;    // 4096
    float* lnb_ = sm + 36864;    // 4096
    float* s8   = sm + 40960;    // 65536
    float* attnw= sm + 106496;   // 512
    float* q8   = sm + 107008;   // 4096
    float* k8   = sm + 111104;   // 4096

    const float bninv = 1.0f / sqrtf(1.0f + 1e-5f);
    const dim3 mgrid(4, 8, 8);   // n-tiles(64) x o-tiles(64) x batch

    auto asri = [&](const float* x, float* out){
        k_gap<<<4096, 64, 0, stream>>>(x, gap);
        k_gemm8<<<2048, 64, 0, stream>>>(gap, qkvw, qkvb, nullptr, 0, 0, qkv, 2048, 0);
        k_asri_attn<<<64, 64, 0, stream>>>(qkv, om);
        k_gemm8<<<512, 64, 0, stream>>>(om, paw, pab, qkv, 1536, 2048, aa, 512, 0);
        k_ln8<<<8, 64, 0, stream>>>(aa, ln1g, ln1b, lnb_);
        k_gemm8<<<512, 64, 0, stream>>>(lnb_, f1w, f1b, nullptr, 0, 0, hb, 512, 1);
        k_gemm8<<<512, 64, 0, stream>>>(hb, f2w, f2b, aa, 0, 512, a2, 512, 0);
        k_ln8<<<8, 64, 0, stream>>>(a2, ln2g, ln2b, lnb_);
        k_gemm8<<<8192, 64, 0, stream>>>(lnb_, c1w, c1b, nullptr, 0, 0, s8, 8192, 0);
        k_up<<<4096, 256, 0, stream>>>(s8, tA);
        k_convm<<<mgrid, 256, 0, stream>>>(tA, c2w, c2b, x, bng, bnb, bninv, out,
                                           CF_BN | CF_RELU | CF_RES);
    };
    asri(xs, sa_s);
    asri(xq, sa_q);

    auto sscm = [&](const float* x1, const float* x2, float* out){
        k_gap<<<4096, 64, 0, stream>>>(x1, gap);
        k_gemm8<<<512, 64, 0, stream>>>(gap, caqw, caqb, nullptr, 0, 0, q8, 512, 0);
        k_gap<<<4096, 64, 0, stream>>>(x2, gap);
        k_gemm8<<<512, 64, 0, stream>>>(gap, cakw, cakb, nullptr, 0, 0, k8, 512, 0);
        k_sscm_attn<<<64, 64, 0, stream>>>(q8, k8, attnw);
        k_convm<<<mgrid, 256, 0, stream>>>(x2, cavw, cavb, nullptr, nullptr, nullptr, 1.f, tA, 0);
        k_sscm_apply<<<4096, 256, 0, stream>>>(attnw, tA, tB);
        k_convm<<<mgrid, 256, 0, stream>>>(tB, capw, capb, nullptr, nullptr, nullptr, 1.f, out, CF_RELU);
    };
    sscm(sa_s, sa_q, ca_s);
    sscm(sa_q, sa_s, ca_q);

    auto pixel = [&](const float* x1, const float* x2, float* out){
        Trio t;
        t.X0 = x1; t.W0 = pqw; t.B0 = pqb; t.O0 = tA;
        t.X1 = x2; t.W1 = pkw; t.B1 = pkb; t.O1 = tB;
        t.X2 = x2; t.W2 = pvw; t.B2 = pvb; t.O2 = tC;
        k_convm_trio<<<dim3(4, 8, 24), 256, 0, stream>>>(t);
        k_zero<<<4096, 256, 0, stream>>>(tD);
        k_pixel_attn<<<dim3(64, 8, 8), 256, 0, stream>>>(tA, tB, tC, tD);
        k_convm<<<mgrid, 256, 0, stream>>>(tD, ppw, ppb, x1, nullptr, nullptr, 1.f, tE, CF_RES);
        k_ln_pix<<<2048, 64, 0, stream>>>(tE, plng, plnb, tA);
        k_convm<<<mgrid, 256, 0, stream>>>(tA, plinw, plinb, nullptr, nullptr, nullptr, 1.f, out, CF_RELU);
    };
    float* out0 = (float*)d_out;
    pixel(sa_s, ca_q, out0);
    pixel(sa_q, ca_s, out0 + (size_t)BIGF);

    (void)in_sizes; (void)n_in; (void)out_size; (void)ws_size;
}

// Round 6
// 670.928 us; speedup vs baseline: 5.1007x; 1.6457x over previous
//
#include <hip/hip_runtime.h>
#include <cmath>

// ---------- constants ----------
#define IMG 131072        // 512*256 per batch image
#define BIGF 1048576      // 8*512*256

#define CF_RELU 1
#define CF_RES  2
#define CF_BN   4

typedef __attribute__((ext_vector_type(8))) short short8;
typedef __attribute__((ext_vector_type(4))) short short4v;
typedef __attribute__((ext_vector_type(4))) float f32x4;

__device__ __forceinline__ float wave_sum(float v){
    #pragma unroll
    for (int off = 32; off; off >>= 1) v += __shfl_xor(v, off);
    return v;
}

__device__ __forceinline__ unsigned short bf16_rn(float x){
    union { float f; unsigned u; } v; v.f = x;
    unsigned r = v.u + 0x7FFF + ((v.u >> 16) & 1);
    return (unsigned short)(r >> 16);
}
__device__ __forceinline__ float bf16_to_f(unsigned short h){
    union { float f; unsigned u; } v; v.u = ((unsigned)h) << 16;
    return v.f;
}

// ---------- GAP: mean over 256 spatial ----------
__global__ __launch_bounds__(64) void k_gap(const float* __restrict__ x, float* __restrict__ out){
    const int bc = blockIdx.x;           // b*512 + c
    const int lane = threadIdx.x;
    const float* p = x + (size_t)bc * 256;
    float s = p[lane] + p[lane + 64] + p[lane + 128] + p[lane + 192];
    s = wave_sum(s);
    if (lane == 0) out[bc] = s * (1.0f / 256.0f);
}

// ---------- tiny GEMM: out[8,O] = in[8,512] @ W[O,512]^T + bias (+add) ----------
__global__ __launch_bounds__(64) void k_gemm8(
    const float* __restrict__ in, const float* __restrict__ W,
    const float* __restrict__ bias, const float* __restrict__ add,
    int add_off, int add_stride, float* __restrict__ out, int O, int relu)
{
    const int o = blockIdx.x;
    const int lane = threadIdx.x;
    const float* wr = W + (size_t)o * 512;
    float acc[8] = {0,0,0,0,0,0,0,0};
    #pragma unroll
    for (int i = 0; i < 8; i++){
        float w = wr[lane + 64*i];
        #pragma unroll
        for (int b = 0; b < 8; b++) acc[b] += w * in[b*512 + lane + 64*i];
    }
    #pragma unroll
    for (int b = 0; b < 8; b++) acc[b] = wave_sum(acc[b]);
    if (lane < 8){
        float v = acc[0];
        #pragma unroll
        for (int b = 1; b < 8; b++) if (lane == b) v = acc[b];
        v += bias[o];
        if (add) v += add[lane*add_stride + add_off + o];
        if (relu) v = fmaxf(v, 0.f);
        out[(size_t)lane * O + o] = v;
    }
}

// ---------- asri batch-axis attention; writes merged o [8,512] ----------
__global__ __launch_bounds__(64) void k_asri_attn(const float* __restrict__ qkv, float* __restrict__ om){
    const int h = blockIdx.x >> 3, b = blockIdx.x & 7, c = threadIdx.x;
    const int ci = c*8 + h;
    float qc = qkv[b*2048 + ci];            // slice 0 = q
    float s[8];
    #pragma unroll
    for (int d = 0; d < 8; d++){
        float p = qc * qkv[d*2048 + 512 + ci];   // slice 1 = k
        p = wave_sum(p);
        s[d] = p * 0.125f;                       // SCALE = 64^-0.5
    }
    float m = s[0];
    #pragma unroll
    for (int d = 1; d < 8; d++) m = fmaxf(m, s[d]);
    float sum = 0.f;
    #pragma unroll
    for (int d = 0; d < 8; d++){ s[d] = __expf(s[d]-m); sum += s[d]; }
    float r = 1.f / sum;
    float oc = 0.f;
    #pragma unroll
    for (int d = 0; d < 8; d++) oc += s[d]*r * qkv[d*2048 + 1024 + ci];  // slice 2 = v
    om[b*512 + ci] = oc;
}

// ---------- LN over 512, 8 rows ----------
__global__ __launch_bounds__(64) void k_ln8(const float* __restrict__ in,
    const float* __restrict__ g, const float* __restrict__ be, float* __restrict__ out)
{
    const int b = blockIdx.x, lane = threadIdx.x;
    float v[8]; float s = 0.f;
    #pragma unroll
    for (int i = 0; i < 8; i++){ v[i] = in[b*512 + lane + 64*i]; s += v[i]; }
    s = wave_sum(s);
    float mean = s * (1.f/512.f);
    float q = 0.f;
    #pragma unroll
    for (int i = 0; i < 8; i++){ float d = v[i]-mean; q += d*d; }
    q = wave_sum(q);
    float rstd = rsqrtf(q*(1.f/512.f) + 1e-5f);
    #pragma unroll
    for (int i = 0; i < 8; i++){
        int c = lane + 64*i;
        out[b*512 + c] = (v[i]-mean)*rstd*g[c] + be[c];
    }
}

// ---------- bilinear upsample 4x4 -> 16x16 align_corners ----------
__global__ __launch_bounds__(256) void k_up(const float* __restrict__ s, float* __restrict__ out){
    const int idx = blockIdx.x*256 + threadIdx.x;       // b*512*256 + ch*256 + y*16 + x
    const int x = idx & 15, y = (idx >> 4) & 15, bc = idx >> 8;
    float px = (float)(x*3) / 15.0f, py = (float)(y*3) / 15.0f;
    int lx = (int)px, ly = (int)py;
    float wx = px - lx, wy = py - ly;
    int hx = min(lx+1, 3), hy = min(ly+1, 3);
    const float* p = s + (size_t)bc * 16;
    float v00 = p[ly*4+lx], v01 = p[ly*4+hx], v10 = p[hy*4+lx], v11 = p[hy*4+hx];
    float a0 = v00*(1.f-wy) + v10*wy;
    float a1 = v01*(1.f-wy) + v11*wy;
    out[idx] = a0*(1.f-wx) + a1*wx;
}

// ---------- zero fill ----------
__global__ __launch_bounds__(256) void k_zero(float* __restrict__ p){
    p[(size_t)blockIdx.x*256 + threadIdx.x] = 0.f;
}

// ---------- conv1x1 via split-bf16 MFMA (proven round 5) ----------
#define LDK 40
__device__ __forceinline__ void convm_body(
    const float* __restrict__ Xb, const float* __restrict__ W,
    const float* __restrict__ bias, const float* __restrict__ resb,
    const float* __restrict__ bng, const float* __restrict__ bnb, float bninv,
    float* __restrict__ outb, int flags, int o0, int n0,
    unsigned short* sAh, unsigned short* sAl,
    unsigned short* sBh, unsigned short* sBl)
{
    const int tid  = threadIdx.x;
    const int wv   = tid >> 6, lane = tid & 63;
    const int quad = lane >> 4, l16 = lane & 15;
    const int wo = (wv >> 1) * 32, wn = (wv & 1) * 32;
    const int so  = tid >> 2;
    const int sk8 = (tid & 3) * 8;
    const int sp  = tid & 15;
    const int sn  = (tid >> 4) * 4;

    const float* wrow = W + (size_t)(o0 + so)*512 + sk8;
    const float* xrow = Xb + (size_t)(2*sp)*256 + n0 + sn;

    f32x4 acc[2][2] = {};
    float4 a0 = *(const float4*)(wrow);
    float4 a1 = *(const float4*)(wrow + 4);
    float4 x0 = *(const float4*)(xrow);
    float4 x1 = *(const float4*)(xrow + 256);

    for (int k0 = 0; k0 < 512; k0 += 32){
        __syncthreads();
        {
            float wa[8] = {a0.x,a0.y,a0.z,a0.w,a1.x,a1.y,a1.z,a1.w};
            #pragma unroll
            for (int j = 0; j < 4; j++){
                unsigned short h0 = bf16_rn(wa[2*j]);
                unsigned short h1 = bf16_rn(wa[2*j+1]);
                unsigned short g0 = bf16_rn(wa[2*j]   - bf16_to_f(h0));
                unsigned short g1 = bf16_rn(wa[2*j+1] - bf16_to_f(h1));
                *(unsigned*)&sAh[so*LDK + sk8 + 2*j] = (unsigned)h0 | ((unsigned)h1 << 16);
                *(unsigned*)&sAl[so*LDK + sk8 + 2*j] = (unsigned)g0 | ((unsigned)g1 << 16);
            }
            float xe[4] = {x0.x,x0.y,x0.z,x0.w};
            float xo[4] = {x1.x,x1.y,x1.z,x1.w};
            #pragma unroll
            for (int j = 0; j < 4; j++){
                unsigned short h0 = bf16_rn(xe[j]);
                unsigned short h1 = bf16_rn(xo[j]);
                unsigned short g0 = bf16_rn(xe[j] - bf16_to_f(h0));
                unsigned short g1 = bf16_rn(xo[j] - bf16_to_f(h1));
                *(unsigned*)&sBh[(sn+j)*LDK + 2*sp] = (unsigned)h0 | ((unsigned)h1 << 16);
                *(unsigned*)&sBl[(sn+j)*LDK + 2*sp] = (unsigned)g0 | ((unsigned)g1 << 16);
            }
        }
        __syncthreads();
        if (k0 + 32 < 512){
            a0 = *(const float4*)(wrow + k0 + 32);
            a1 = *(const float4*)(wrow + k0 + 36);
            x0 = *(const float4*)(xrow + (size_t)(k0+32)*256);
            x1 = *(const float4*)(xrow + (size_t)(k0+32)*256 + 256);
        }
        short8 ah[2], al[2], bh[2], bl[2];
        #pragma unroll
        for (int t = 0; t < 2; t++){
            int ai = (wo + 16*t + l16)*LDK + quad*8;
            ah[t] = *(const short8*)&sAh[ai];
            al[t] = *(const short8*)&sAl[ai];
            int bi = (wn + 16*t + l16)*LDK + quad*8;
            bh[t] = *(const short8*)&sBh[bi];
            bl[t] = *(const short8*)&sBl[bi];
        }
        #pragma unroll
        for (int mt = 0; mt < 2; mt++){
            #pragma unroll
            for (int nt = 0; nt < 2; nt++){
                acc[mt][nt] = __builtin_amdgcn_mfma_f32_16x16x32_bf16(ah[mt], bh[nt], acc[mt][nt], 0, 0, 0);
                acc[mt][nt] = __builtin_amdgcn_mfma_f32_16x16x32_bf16(ah[mt], bl[nt], acc[mt][nt], 0, 0, 0);
                acc[mt][nt] = __builtin_amdgcn_mfma_f32_16x16x32_bf16(al[mt], bh[nt], acc[mt][nt], 0, 0, 0);
            }
        }
    }
    #pragma unroll
    for (int mt = 0; mt < 2; mt++){
        #pragma unroll
        for (int nt = 0; nt < 2; nt++){
            const int n  = n0 + wn + 16*nt + l16;
            const int ob = o0 + wo + 16*mt + quad*4;
            #pragma unroll
            for (int r = 0; r < 4; r++){
                const int o = ob + r;
                float v = acc[mt][nt][r] + bias[o];
                if (flags & CF_BN)   v = v*(bninv*bng[o]) + bnb[o];
                if (flags & CF_RELU) v = fmaxf(v, 0.f);
                if (flags & CF_RES)  v += resb[(size_t)o*256 + n];
                outb[(size_t)o*256 + n] = v;
            }
        }
    }
}

__global__ __launch_bounds__(256) void k_convm(
    const float* __restrict__ X, const float* __restrict__ W,
    const float* __restrict__ bias, const float* __restrict__ res,
    const float* __restrict__ bng, const float* __restrict__ bnb, float bninv,
    float* __restrict__ out, int flags)
{
    __shared__ unsigned short sAh[64*LDK], sAl[64*LDK], sBh[64*LDK], sBl[64*LDK];
    const int b = blockIdx.z, o0 = blockIdx.y*64, n0 = blockIdx.x*64;
    convm_body(X + (size_t)b*IMG, W, bias, res ? res + (size_t)b*IMG : nullptr,
               bng, bnb, bninv, out + (size_t)b*IMG, flags, o0, n0,
               sAh, sAl, sBh, sBl);
}

struct Trio {
    const float *X0,*X1,*X2, *W0,*W1,*W2, *B0,*B1,*B2;
    float *O0,*O1,*O2;
};
__global__ __launch_bounds__(256) void k_convm_trio(Trio t)
{
    __shared__ unsigned short sAh[64*LDK], sAl[64*LDK], sBh[64*LDK], sBl[64*LDK];
    const int g = blockIdx.z >> 3, b = blockIdx.z & 7;
    const int o0 = blockIdx.y*64, n0 = blockIdx.x*64;
    const float* X = (g==0) ? t.X0 : (g==1) ? t.X1 : t.X2;
    const float* W = (g==0) ? t.W0 : (g==1) ? t.W1 : t.W2;
    const float* B = (g==0) ? t.B0 : (g==1) ? t.B1 : t.B2;
    float*       O = (g==0) ? t.O0 : (g==1) ? t.O1 : t.O2;
    convm_body(X + (size_t)b*IMG, W, B, nullptr, nullptr, nullptr, 1.f,
               O + (size_t)b*IMG, 0, o0, n0, sAh, sAl, sBh, sBl);
}

// ---------- sscm attention weights [h][b][d] ----------
__global__ __launch_bounds__(64) void k_sscm_attn(const float* __restrict__ q8,
    const float* __restrict__ k8, float* __restrict__ attnw)
{
    const int h = blockIdx.x >> 3, b = blockIdx.x & 7, c = threadIdx.x;
    const int ci = c*8 + h;
    float qc = q8[b*512 + ci];
    float s[8];
    #pragma unroll
    for (int d = 0; d < 8; d++){
        float p = qc * k8[d*512 + ci];
        p = wave_sum(p);
        s[d] = p * 0.125f;
    }
    float m = s[0];
    #pragma unroll
    for (int d = 1; d < 8; d++) m = fmaxf(m, s[d]);
    float sum = 0.f;
    #pragma unroll
    for (int d = 0; d < 8; d++){ s[d] = __expf(s[d]-m); sum += s[d]; }
    float r = 1.f/sum;
    if (c < 8){
        float v = s[0];
        #pragma unroll
        for (int d = 1; d < 8; d++) if (c == d) v = s[d];
        attnw[blockIdx.x*8 + c] = v*r;
    }
}

// ---------- sscm apply ----------
__global__ __launch_bounds__(256) void k_sscm_apply(const float* __restrict__ attnw,
    const float* __restrict__ v, float* __restrict__ out)
{
    const int idx = blockIdx.x*256 + threadIdx.x;
    const int pix = idx & 255, e = (idx >> 8) & 511, b = idx >> 17;
    const int h = e & 7;
    const float* aw = attnw + (h*8 + b)*8;
    float acc = 0.f;
    #pragma unroll
    for (int d = 0; d < 8; d++) acc += aw[d] * v[(size_t)d*IMG + (size_t)e*256 + pix];
    out[idx] = acc;
}

// ---------- pixel cross-batch attention v4: MFMA ----------
// block = (nt, d, b, h): 64 queries, one key batch d.
// S^T = K*Q^T via split-bf16 (3 MFMAs, fp32-accurate scores); softmax in regs
// (lane holds col q = wv*16+l16, m spread over quads/regs -> shfl_xor 16,32);
// O^T = V^T*P^T with split V, bf16 P. d-accumulation via fp32 global atomics.
// Frag mappings identical to convm (A/B: row=l16, 8k at quad*8; D: col=l16,
// row=quad*4+reg) -- HW-verified by the passing conv kernel.
__global__ __launch_bounds__(256) void k_pixel_mfma(
    const float* __restrict__ Q, const float* __restrict__ K,
    const float* __restrict__ V, float* __restrict__ O)
{
    __shared__ char smem[61440];
    // QK phase aliases
    unsigned short* sQh = (unsigned short*)smem;      // [2 ks][64 q][40]
    unsigned short* sQl = sQh + 2*64*40;
    unsigned short* sKh = sQl + 2*64*40;              // [2 ks][128 m][40]
    unsigned short* sKl = sKh + 2*128*40;
    // PV phase aliases (reuse; valid after post-softmax barrier)
    unsigned short* sP  = (unsigned short*)smem;      // [4 ks][64 q][40]
    unsigned short* sVh = sP  + 4*64*40;              // [4 ks][64 c][40]
    unsigned short* sVl = sVh + 4*64*40;

    const int nt = blockIdx.x & 3, d = blockIdx.x >> 2;
    const int b = blockIdx.y, h = blockIdx.z;
    const int tid = threadIdx.x;
    const int wv = tid >> 6, lane = tid & 63;
    const int quad = lane >> 4, l16 = lane & 15;
    const int n0 = nt * 64;
    const size_t bQ = (size_t)b * IMG;
    const size_t bK = (size_t)d * IMG;

    // ---- stage Q (64q x 64c, split hi/lo), rows q ----
    {
        const int q = tid & 63, c0 = tid >> 6;
        #pragma unroll
        for (int r = 0; r < 16; r++){
            int c = c0 + 4*r;
            float v = Q[bQ + (size_t)(c*8+h)*256 + n0 + q];
            unsigned short hi = bf16_rn(v);
            unsigned short lo = bf16_rn(v - bf16_to_f(hi));
            int idx = (c>>5)*2560 + q*40 + (c&31);
            sQh[idx] = hi; sQl[idx] = lo;
        }
    }
    // ---- stage K half 0 ----
    {
        const int mloc = tid & 127, cb0 = tid >> 7;
        #pragma unroll
        for (int p = 0; p < 4; p++){
            int cb = cb0 + 2*p;
            short8 hi8, lo8;
            #pragma unroll
            for (int j = 0; j < 8; j++){
                float v = K[bK + (size_t)((cb*8+j)*8+h)*256 + mloc];
                unsigned short hv = bf16_rn(v);
                hi8[j] = (short)hv;
                lo8[j] = (short)bf16_rn(v - bf16_to_f(hv));
            }
            int idx = (cb>>2)*5120 + mloc*40 + (cb&3)*8;
            *(short8*)&sKh[idx] = hi8;
            *(short8*)&sKl[idx] = lo8;
        }
    }
    __syncthreads();

    // ---- Q fragments (persist in regs across both halves) ----
    short8 bqh[2], bql[2];
    #pragma unroll
    for (int ks = 0; ks < 2; ks++){
        int idx = ks*2560 + (wv*16 + l16)*40 + quad*8;
        bqh[ks] = *(const short8*)&sQh[idx];
        bql[ks] = *(const short8*)&sQl[idx];
    }

    f32x4 S[16] = {};   // S^T tiles: m = quad*4+reg + 16*mt (mt=hm*8+mtl), q = wv*16+l16
    #pragma unroll
    for (int hm = 0; hm < 2; hm++){
        if (hm == 1){
            __syncthreads();
            const int mloc = tid & 127, cb0 = tid >> 7;
            #pragma unroll
            for (int p = 0; p < 4; p++){
                int cb = cb0 + 2*p;
                short8 hi8, lo8;
                #pragma unroll
                for (int j = 0; j < 8; j++){
                    float v = K[bK + (size_t)((cb*8+j)*8+h)*256 + 128 + mloc];
                    unsigned short hv = bf16_rn(v);
                    hi8[j] = (short)hv;
                    lo8[j] = (short)bf16_rn(v - bf16_to_f(hv));
                }
                int idx = (cb>>2)*5120 + mloc*40 + (cb&3)*8;
                *(short8*)&sKh[idx] = hi8;
                *(short8*)&sKl[idx] = lo8;
            }
            __syncthreads();
        }
        #pragma unroll
        for (int mtl = 0; mtl < 8; mtl++){
            #pragma unroll
            for (int ks = 0; ks < 2; ks++){
                int idx = ks*5120 + (mtl*16 + l16)*40 + quad*8;
                short8 ah = *(const short8*)&sKh[idx];
                short8 al = *(const short8*)&sKl[idx];
                S[hm*8+mtl] = __builtin_amdgcn_mfma_f32_16x16x32_bf16(ah, bqh[ks], S[hm*8+mtl], 0, 0, 0);
                S[hm*8+mtl] = __builtin_amdgcn_mfma_f32_16x16x32_bf16(ah, bql[ks], S[hm*8+mtl], 0, 0, 0);
                S[hm*8+mtl] = __builtin_amdgcn_mfma_f32_16x16x32_bf16(al, bqh[ks], S[hm*8+mtl], 0, 0, 0);
            }
        }
    }

    // ---- softmax over m (all 256) per q-column; NO scale (matches source) ----
    {
        float mx = -3.4e38f;
        #pragma unroll
        for (int t = 0; t < 16; t++)
            #pragma unroll
            for (int r = 0; r < 4; r++) mx = fmaxf(mx, S[t][r]);
        mx = fmaxf(mx, __shfl_xor(mx, 16));
        mx = fmaxf(mx, __shfl_xor(mx, 32));
        float sum = 0.f;
        #pragma unroll
        for (int t = 0; t < 16; t++)
            #pragma unroll
            for (int r = 0; r < 4; r++){ S[t][r] = __expf(S[t][r]-mx); sum += S[t][r]; }
        sum += __shfl_xor(sum, 16);
        sum += __shfl_xor(sum, 32);
        float rr = 1.f/sum;
        #pragma unroll
        for (int t = 0; t < 16; t++)
            #pragma unroll
            for (int r = 0; r < 4; r++) S[t][r] *= rr;
    }
    __syncthreads();   // all QK LDS reads done; safe to overwrite for PV

    f32x4 oac[4] = {};  // O^T tiles: c = quad*4+reg + 16*ct, q = wv*16+l16
    #pragma unroll
    for (int hm = 0; hm < 2; hm++){
        // write P half (bf16, rows q): m = quad*4+reg + 16*mtl
        #pragma unroll
        for (int mtl = 0; mtl < 8; mtl++){
            short4v p4;
            #pragma unroll
            for (int r = 0; r < 4; r++) p4[r] = (short)bf16_rn(S[hm*8+mtl][r]);
            int idx = (mtl>>1)*2560 + (wv*16 + l16)*40 + 16*(mtl&1) + quad*4;
            *(short4v*)&sP[idx] = p4;
        }
        // stage V half (rows c, split hi/lo)
        {
            const int mp = tid & 63, c0 = tid >> 6;
            #pragma unroll
            for (int p = 0; p < 16; p++){
                int c = c0 + 4*p;
                float2 vv = *(const float2*)&V[bK + (size_t)(c*8+h)*256 + hm*128 + 2*mp];
                unsigned short h0 = bf16_rn(vv.x), h1 = bf16_rn(vv.y);
                unsigned short g0 = bf16_rn(vv.x - bf16_to_f(h0));
                unsigned short g1 = bf16_rn(vv.y - bf16_to_f(h1));
                int idx = (mp>>4)*2560 + c*40 + ((2*mp)&31);
                *(unsigned*)&sVh[idx] = (unsigned)h0 | ((unsigned)h1 << 16);
                *(unsigned*)&sVl[idx] = (unsigned)g0 | ((unsigned)g1 << 16);
            }
        }
        __syncthreads();
        #pragma unroll
        for (int ks = 0; ks < 4; ks++){
            int pidx = ks*2560 + (wv*16 + l16)*40 + quad*8;
            short8 bp = *(const short8*)&sP[pidx];
            #pragma unroll
            for (int ct = 0; ct < 4; ct++){
                int vidx = ks*2560 + (ct*16 + l16)*40 + quad*8;
                short8 vh = *(const short8*)&sVh[vidx];
                short8 vl = *(const short8*)&sVl[vidx];
                oac[ct] = __builtin_amdgcn_mfma_f32_16x16x32_bf16(vh, bp, oac[ct], 0, 0, 0);
                oac[ct] = __builtin_amdgcn_mfma_f32_16x16x32_bf16(vl, bp, oac[ct], 0, 0, 0);
            }
        }
        __syncthreads();
    }

    // ---- accumulate over d via atomics; q = wv*16+l16 (64B-coalesced groups) ----
    const int q = n0 + wv*16 + l16;
    #pragma unroll
    for (int ct = 0; ct < 4; ct++){
        #pragma unroll
        for (int r = 0; r < 4; r++){
            int c = ct*16 + quad*4 + r;
            unsafeAtomicAdd(&O[bQ + (size_t)(c*8+h)*256 + q], oac[ct][r]);
        }
    }
}

// ---------- LN over channels (strided), keeps [b][c][n] layout ----------
__global__ __launch_bounds__(64) void k_ln_pix(const float* __restrict__ in,
    const float* __restrict__ g, const float* __restrict__ be, float* __restrict__ out)
{
    const int bn = blockIdx.x;                 // b*256 + n
    const int b = bn >> 8, n = bn & 255;
    const int lane = threadIdx.x;
    const float* p = in + (size_t)b*IMG + n;
    float v[8]; float s = 0.f;
    #pragma unroll
    for (int i = 0; i < 8; i++){ v[i] = p[(size_t)(lane + 64*i)*256]; s += v[i]; }
    s = wave_sum(s);
    float mean = s * (1.f/512.f);
    float q = 0.f;
    #pragma unroll
    for (int i = 0; i < 8; i++){ float d = v[i]-mean; q += d*d; }
    q = wave_sum(q);
    float rstd = rsqrtf(q*(1.f/512.f) + 1e-5f);
    #pragma unroll
    for (int i = 0; i < 8; i++){
        int c = lane + 64*i;
        out[(size_t)b*IMG + (size_t)c*256 + n] = (v[i]-mean)*rstd*g[c] + be[c];
    }
}

// ---------- host orchestration ----------
extern "C" void kernel_launch(void* const* d_in, const int* in_sizes, int n_in,
                              void* d_out, int out_size, void* d_ws, size_t ws_size,
                              hipStream_t stream)
{
    const float* xs    = (const float*)d_in[0];
    const float* xq    = (const float*)d_in[1];
    const float* qkvw  = (const float*)d_in[2];  const float* qkvb = (const float*)d_in[3];
    const float* paw   = (const float*)d_in[4];  const float* pab  = (const float*)d_in[5];
    const float* ln1g  = (const float*)d_in[6];  const float* ln1b = (const float*)d_in[7];
    const float* f1w   = (const float*)d_in[8];  const float* f1b  = (const float*)d_in[9];
    const float* f2w   = (const float*)d_in[10]; const float* f2b  = (const float*)d_in[11];
    const float* ln2g  = (const float*)d_in[12]; const float* ln2b = (const float*)d_in[13];
    const float* c1w   = (const float*)d_in[14]; const float* c1b  = (const float*)d_in[15];
    const float* c2w   = (const float*)d_in[16]; const float* c2b  = (const float*)d_in[17];
    const float* bng   = (const float*)d_in[18]; const float* bnb  = (const float*)d_in[19];
    const float* caqw  = (const float*)d_in[20]; const float* caqb = (const float*)d_in[21];
    const float* cakw  = (const float*)d_in[22]; const float* cakb = (const float*)d_in[23];
    const float* cavw  = (const float*)d_in[24]; const float* cavb = (const float*)d_in[25];
    const float* capw  = (const float*)d_in[26]; const float* capb = (const float*)d_in[27];
    const float* pqw   = (const float*)d_in[28]; const float* pqb  = (const float*)d_in[29];
    const float* pkw   = (const float*)d_in[30]; const float* pkb  = (const float*)d_in[31];
    const float* pvw   = (const float*)d_in[32]; const float* pvb  = (const float*)d_in[33];
    const float* ppw   = (const float*)d_in[34]; const float* ppb  = (const float*)d_in[35];
    const float* plng  = (const float*)d_in[36]; const float* plnb = (const float*)d_in[37];
    const float* plinw = (const float*)d_in[38]; const float* plinb= (const float*)d_in[39];

    float* ws = (float*)d_ws;
    float* sa_s = ws;
    float* sa_q = ws + 1*(size_t)BIGF;
    float* ca_s = ws + 2*(size_t)BIGF;
    float* ca_q = ws + 3*(size_t)BIGF;
    float* tA   = ws + 4*(size_t)BIGF;
    float* tB   = ws + 5*(size_t)BIGF;
    float* tC   = ws + 6*(size_t)BIGF;
    float* tD   = ws + 7*(size_t)BIGF;
    float* tE   = ws + 8*(size_t)BIGF;
    float* sm   = ws + 9*(size_t)BIGF;
    float* gap  = sm;
    float* qkv  = sm + 4096;
    float* om   = sm + 20480;
    float* aa   = sm + 24576;
    float* hb   = sm + 28672;
    float* a2   = sm + 32768;
    float* lnb_ = sm + 36864;
    float* s8   = sm + 40960;
    float* attnw= sm + 106496;
    float* q8   = sm + 107008;
    float* k8   = sm + 111104;

    const float bninv = 1.0f / sqrtf(1.0f + 1e-5f);
    const dim3 mgrid(4, 8, 8);

    auto asri = [&](const float* x, float* out){
        k_gap<<<4096, 64, 0, stream>>>(x, gap);
        k_gemm8<<<2048, 64, 0, stream>>>(gap, qkvw, qkvb, nullptr, 0, 0, qkv, 2048, 0);
        k_asri_attn<<<64, 64, 0, stream>>>(qkv, om);
        k_gemm8<<<512, 64, 0, stream>>>(om, paw, pab, qkv, 1536, 2048, aa, 512, 0);
        k_ln8<<<8, 64, 0, stream>>>(aa, ln1g, ln1b, lnb_);
        k_gemm8<<<512, 64, 0, stream>>>(lnb_, f1w, f1b, nullptr, 0, 0, hb, 512, 1);
        k_gemm8<<<512, 64, 0, stream>>>(hb, f2w, f2b, aa, 0, 512, a2, 512, 0);
        k_ln8<<<8, 64, 0, stream>>>(a2, ln2g, ln2b, lnb_);
        k_gemm8<<<8192, 64, 0, stream>>>(lnb_, c1w, c1b, nullptr, 0, 0, s8, 8192, 0);
        k_up<<<4096, 256, 0, stream>>>(s8, tA);
        k_convm<<<mgrid, 256, 0, stream>>>(tA, c2w, c2b, x, bng, bnb, bninv, out,
                                           CF_BN | CF_RELU | CF_RES);
    };
    asri(xs, sa_s);
    asri(xq, sa_q);

    auto sscm = [&](const float* x1, const float* x2, float* out){
        k_gap<<<4096, 64, 0, stream>>>(x1, gap);
        k_gemm8<<<512, 64, 0, stream>>>(gap, caqw, caqb, nullptr, 0, 0, q8, 512, 0);
        k_gap<<<4096, 64, 0, stream>>>(x2, gap);
        k_gemm8<<<512, 64, 0, stream>>>(gap, cakw, cakb, nullptr, 0, 0, k8, 512, 0);
        k_sscm_attn<<<64, 64, 0, stream>>>(q8, k8, attnw);
        k_convm<<<mgrid, 256, 0, stream>>>(x2, cavw, cavb, nullptr, nullptr, nullptr, 1.f, tA, 0);
        k_sscm_apply<<<4096, 256, 0, stream>>>(attnw, tA, tB);
        k_convm<<<mgrid, 256, 0, stream>>>(tB, capw, capb, nullptr, nullptr, nullptr, 1.f, out, CF_RELU);
    };
    sscm(sa_s, sa_q, ca_s);
    sscm(sa_q, sa_s, ca_q);

    auto pixel = [&](const float* x1, const float* x2, float* out){
        Trio t;
        t.X0 = x1; t.W0 = pqw; t.B0 = pqb; t.O0 = tA;
        t.X1 = x2; t.W1 = pkw; t.B1 = pkb; t.O1 = tB;
        t.X2 = x2; t.W2 = pvw; t.B2 = pvb; t.O2 = tC;
        k_convm_trio<<<dim3(4, 8, 24), 256, 0, stream>>>(t);
        k_zero<<<4096, 256, 0, stream>>>(tD);
        k_pixel_mfma<<<dim3(32, 8, 8), 256, 0, stream>>>(tA, tB, tC, tD);
        k_convm<<<mgrid, 256, 0, stream>>>(tD, ppw, ppb, x1, nullptr, nullptr, 1.f, tE, CF_RES);
        k_ln_pix<<<2048, 64, 0, stream>>>(tE, plng, plnb, tA);
        k_convm<<<mgrid, 256, 0, stream>>>(tA, plinw, plinb, nullptr, nullptr, nullptr, 1.f, out, CF_RELU);
    };
    float* out0 = (float*)d_out;
    pixel(sa_s, ca_q, out0);
    pixel(sa_q, ca_s, out0 + (size_t)BIGF);

    (void)in_sizes; (void)n_in; (void)out_size; (void)ws_size;
}

// Round 7
// 480.699 us; speedup vs baseline: 7.1193x; 1.3957x over previous
//
#include <hip/hip_runtime.h>
#include <cmath>

// ---------- constants ----------
#define IMG 131072        // 512*256 per batch image
#define BIGF 1048576      // 8*512*256

#define CF_RELU 1
#define CF_RES  2
#define CF_BN   4

typedef __attribute__((ext_vector_type(8))) short short8;
typedef __attribute__((ext_vector_type(4))) short short4v;
typedef __attribute__((ext_vector_type(4))) float f32x4;

__device__ __forceinline__ float wave_sum(float v){
    #pragma unroll
    for (int off = 32; off; off >>= 1) v += __shfl_xor(v, off);
    return v;
}

__device__ __forceinline__ unsigned short bf16_rn(float x){
    union { float f; unsigned u; } v; v.f = x;
    unsigned r = v.u + 0x7FFF + ((v.u >> 16) & 1);
    return (unsigned short)(r >> 16);
}
__device__ __forceinline__ float bf16_to_f(unsigned short h){
    union { float f; unsigned u; } v; v.u = ((unsigned)h) << 16;
    return v.f;
}

// ---------- job structs (paired launches across the two branches) ----------
struct GapJobs  { const float* x[2]; float* o[2]; };
struct G8Job    { const float* in; const float* W; const float* bias; const float* add; float* out; };
struct G8Jobs   { G8Job j[4]; };
struct AAJobs   { const float* qkv[2]; float* om[2]; };
struct LnJobs   { const float* in[2]; float* out[2]; };
struct UpJobs   { const float* in[2]; float* out[2]; };
struct SAJobs   { const float* q8[2]; const float* k8[2]; float* aw[2]; };
struct SPJobs   { const float* aw[2]; const float* v[2]; float* out[2]; };
struct ZJobs    { float* p[2]; };
struct ConvJob  { const float* X; const float* W; const float* B; const float* R;
                  const float* bng; const float* bnb; float* O; int flags; };
struct ConvJobs { ConvJob j[6]; };
struct PixJob   { const float* Q; const float* K; const float* V; float* O; };
struct PixJobs  { PixJob j[2]; };

// ---------- GAP: mean over 256 spatial ----------
__global__ __launch_bounds__(64) void k_gap(GapJobs jo){
    const int br = blockIdx.y;
    const int bc = blockIdx.x;           // b*512 + c
    const int lane = threadIdx.x;
    const float* p = jo.x[br] + (size_t)bc * 256;
    float s = p[lane] + p[lane + 64] + p[lane + 128] + p[lane + 192];
    s = wave_sum(s);
    if (lane == 0) jo.o[br][bc] = s * (1.0f / 256.0f);
}

// ---------- tiny GEMM: out[8,O] = in[8,512] @ W[O,512]^T + bias (+add) ----------
__global__ __launch_bounds__(64) void k_gemm8(G8Jobs jo, int add_off, int add_stride, int O, int relu){
    const G8Job j = jo.j[blockIdx.y];
    const int o = blockIdx.x;
    const int lane = threadIdx.x;
    const float* wr = j.W + (size_t)o * 512;
    float acc[8] = {0,0,0,0,0,0,0,0};
    #pragma unroll
    for (int i = 0; i < 8; i++){
        float w = wr[lane + 64*i];
        #pragma unroll
        for (int b = 0; b < 8; b++) acc[b] += w * j.in[b*512 + lane + 64*i];
    }
    #pragma unroll
    for (int b = 0; b < 8; b++) acc[b] = wave_sum(acc[b]);
    if (lane < 8){
        float v = acc[0];
        #pragma unroll
        for (int b = 1; b < 8; b++) if (lane == b) v = acc[b];
        v += j.bias[o];
        if (j.add) v += j.add[lane*add_stride + add_off + o];
        if (relu) v = fmaxf(v, 0.f);
        j.out[(size_t)lane * O + o] = v;
    }
}

// ---------- asri batch-axis attention; writes merged o [8,512] ----------
__global__ __launch_bounds__(64) void k_asri_attn(AAJobs jo){
    const int br = blockIdx.y;
    const float* qkv = jo.qkv[br];
    const int h = blockIdx.x >> 3, b = blockIdx.x & 7, c = threadIdx.x;
    const int ci = c*8 + h;
    float qc = qkv[b*2048 + ci];
    float s[8];
    #pragma unroll
    for (int d = 0; d < 8; d++){
        float p = qc * qkv[d*2048 + 512 + ci];
        p = wave_sum(p);
        s[d] = p * 0.125f;
    }
    float m = s[0];
    #pragma unroll
    for (int d = 1; d < 8; d++) m = fmaxf(m, s[d]);
    float sum = 0.f;
    #pragma unroll
    for (int d = 0; d < 8; d++){ s[d] = __expf(s[d]-m); sum += s[d]; }
    float r = 1.f / sum;
    float oc = 0.f;
    #pragma unroll
    for (int d = 0; d < 8; d++) oc += s[d]*r * qkv[d*2048 + 1024 + ci];
    jo.om[br][b*512 + ci] = oc;
}

// ---------- LN over 512, 8 rows ----------
__global__ __launch_bounds__(64) void k_ln8(LnJobs jo,
    const float* __restrict__ g, const float* __restrict__ be)
{
    const int br = blockIdx.y;
    const int b = blockIdx.x, lane = threadIdx.x;
    const float* in = jo.in[br];
    float v[8]; float s = 0.f;
    #pragma unroll
    for (int i = 0; i < 8; i++){ v[i] = in[b*512 + lane + 64*i]; s += v[i]; }
    s = wave_sum(s);
    float mean = s * (1.f/512.f);
    float q = 0.f;
    #pragma unroll
    for (int i = 0; i < 8; i++){ float d = v[i]-mean; q += d*d; }
    q = wave_sum(q);
    float rstd = rsqrtf(q*(1.f/512.f) + 1e-5f);
    #pragma unroll
    for (int i = 0; i < 8; i++){
        int c = lane + 64*i;
        jo.out[br][b*512 + c] = (v[i]-mean)*rstd*g[c] + be[c];
    }
}

// ---------- bilinear upsample 4x4 -> 16x16 align_corners ----------
__global__ __launch_bounds__(256) void k_up(UpJobs jo){
    const int br = blockIdx.y;
    const int idx = blockIdx.x*256 + threadIdx.x;
    const int x = idx & 15, y = (idx >> 4) & 15, bc = idx >> 8;
    float px = (float)(x*3) / 15.0f, py = (float)(y*3) / 15.0f;
    int lx = (int)px, ly = (int)py;
    float wx = px - lx, wy = py - ly;
    int hx = min(lx+1, 3), hy = min(ly+1, 3);
    const float* p = jo.in[br] + (size_t)bc * 16;
    float v00 = p[ly*4+lx], v01 = p[ly*4+hx], v10 = p[hy*4+lx], v11 = p[hy*4+hx];
    float a0 = v00*(1.f-wy) + v10*wy;
    float a1 = v01*(1.f-wy) + v11*wy;
    jo.out[br][idx] = a0*(1.f-wx) + a1*wx;
}

// ---------- zero fill ----------
__global__ __launch_bounds__(256) void k_zero(ZJobs jo){
    jo.p[blockIdx.y][(size_t)blockIdx.x*256 + threadIdx.x] = 0.f;
}

// ---------- conv1x1 via split-bf16 MFMA, v3: 512 thr, K-split across 2 wave-groups ----------
// Each 4-wave group handles half the K range (256) into its own LDS region; group 1's
// accumulators are reduced into group 0 via LDS, group 0 runs the epilogue.
// 8 waves/block, grid 256/job -> 2 waves/SIMD (latency hiding; round-6 convm had 1).
#define LDK 40
__device__ __forceinline__ void convm_body(
    const float* __restrict__ Xb, const float* __restrict__ W,
    const float* __restrict__ bias, const float* __restrict__ resb,
    const float* __restrict__ bng, const float* __restrict__ bnb, float bninv,
    float* __restrict__ outb, int flags, int o0, int n0, unsigned short* lds)
{
    const int tid512 = threadIdx.x;
    const int g   = tid512 >> 8;          // K-group
    const int tid = tid512 & 255;
    unsigned short* sAh = lds + g*10240;
    unsigned short* sAl = sAh + 2560;
    unsigned short* sBh = sAl + 2560;
    unsigned short* sBl = sBh + 2560;
    const int wv = tid >> 6, lane = tid & 63;
    const int quad = lane >> 4, l16 = lane & 15;
    const int wo = (wv >> 1) * 32, wn = (wv & 1) * 32;
    const int so  = tid >> 2, sk8 = (tid & 3) * 8;
    const int sp  = tid & 15, sn  = (tid >> 4) * 4;

    const float* wrow = W + (size_t)(o0 + so)*512 + g*256 + sk8;
    const float* xrow = Xb + (size_t)(g*256 + 2*sp)*256 + n0 + sn;

    f32x4 acc[2][2] = {};
    float4 a0 = *(const float4*)(wrow);
    float4 a1 = *(const float4*)(wrow + 4);
    float4 x0 = *(const float4*)(xrow);
    float4 x1 = *(const float4*)(xrow + 256);

    for (int k0 = 0; k0 < 256; k0 += 32){
        __syncthreads();
        {
            float wa[8] = {a0.x,a0.y,a0.z,a0.w,a1.x,a1.y,a1.z,a1.w};
            #pragma unroll
            for (int j = 0; j < 4; j++){
                unsigned short h0 = bf16_rn(wa[2*j]);
                unsigned short h1 = bf16_rn(wa[2*j+1]);
                unsigned short g0 = bf16_rn(wa[2*j]   - bf16_to_f(h0));
                unsigned short g1 = bf16_rn(wa[2*j+1] - bf16_to_f(h1));
                *(unsigned*)&sAh[so*LDK + sk8 + 2*j] = (unsigned)h0 | ((unsigned)h1 << 16);
                *(unsigned*)&sAl[so*LDK + sk8 + 2*j] = (unsigned)g0 | ((unsigned)g1 << 16);
            }
            float xe[4] = {x0.x,x0.y,x0.z,x0.w};
            float xo[4] = {x1.x,x1.y,x1.z,x1.w};
            #pragma unroll
            for (int j = 0; j < 4; j++){
                unsigned short h0 = bf16_rn(xe[j]);
                unsigned short h1 = bf16_rn(xo[j]);
                unsigned short g0 = bf16_rn(xe[j] - bf16_to_f(h0));
                unsigned short g1 = bf16_rn(xo[j] - bf16_to_f(h1));
                *(unsigned*)&sBh[(sn+j)*LDK + 2*sp] = (unsigned)h0 | ((unsigned)h1 << 16);
                *(unsigned*)&sBl[(sn+j)*LDK + 2*sp] = (unsigned)g0 | ((unsigned)g1 << 16);
            }
        }
        __syncthreads();
        if (k0 + 32 < 256){
            a0 = *(const float4*)(wrow + k0 + 32);
            a1 = *(const float4*)(wrow + k0 + 36);
            x0 = *(const float4*)(xrow + (size_t)(k0+32)*256);
            x1 = *(const float4*)(xrow + (size_t)(k0+32)*256 + 256);
        }
        short8 ah[2], al[2], bh[2], bl[2];
        #pragma unroll
        for (int t = 0; t < 2; t++){
            int ai = (wo + 16*t + l16)*LDK + quad*8;
            ah[t] = *(const short8*)&sAh[ai];
            al[t] = *(const short8*)&sAl[ai];
            int bi = (wn + 16*t + l16)*LDK + quad*8;
            bh[t] = *(const short8*)&sBh[bi];
            bl[t] = *(const short8*)&sBl[bi];
        }
        #pragma unroll
        for (int mt = 0; mt < 2; mt++){
            #pragma unroll
            for (int nt = 0; nt < 2; nt++){
                acc[mt][nt] = __builtin_amdgcn_mfma_f32_16x16x32_bf16(ah[mt], bh[nt], acc[mt][nt], 0, 0, 0);
                acc[mt][nt] = __builtin_amdgcn_mfma_f32_16x16x32_bf16(ah[mt], bl[nt], acc[mt][nt], 0, 0, 0);
                acc[mt][nt] = __builtin_amdgcn_mfma_f32_16x16x32_bf16(al[mt], bh[nt], acc[mt][nt], 0, 0, 0);
            }
        }
    }
    // ---- cross-group reduction (stride-20 float rows: conflict-benign) ----
    __syncthreads();
    float* red = (float*)lds;
    if (g == 1){
        float* r = red + tid*20;
        #pragma unroll
        for (int mt = 0; mt < 2; mt++)
            #pragma unroll
            for (int nt = 0; nt < 2; nt++)
                *(f32x4*)(r + (mt*2+nt)*4) = acc[mt][nt];
    }
    __syncthreads();
    if (g == 0){
        float* r = red + tid*20;
        #pragma unroll
        for (int mt = 0; mt < 2; mt++)
            #pragma unroll
            for (int nt = 0; nt < 2; nt++){
                f32x4 o4 = *(const f32x4*)(r + (mt*2+nt)*4);
                acc[mt][nt] += o4;
            }
        #pragma unroll
        for (int mt = 0; mt < 2; mt++){
            #pragma unroll
            for (int nt = 0; nt < 2; nt++){
                const int n  = n0 + wn + 16*nt + l16;
                const int ob = o0 + wo + 16*mt + quad*4;
                #pragma unroll
                for (int rr = 0; rr < 4; rr++){
                    const int o = ob + rr;
                    float v = acc[mt][nt][rr] + bias[o];
                    if (flags & CF_BN)   v = v*(bninv*bng[o]) + bnb[o];
                    if (flags & CF_RELU) v = fmaxf(v, 0.f);
                    if (flags & CF_RES)  v += resb[(size_t)o*256 + n];
                    outb[(size_t)o*256 + n] = v;
                }
            }
        }
    }
}

__global__ __launch_bounds__(512) void k_convm(ConvJobs jo, float bninv)
{
    __shared__ unsigned short lds[20480];   // 40 KB: 2 groups x 4 planes x 64x40
    const int z = blockIdx.z;
    const ConvJob j = jo.j[z >> 3];
    const int b = z & 7;
    convm_body(j.X + (size_t)b*IMG, j.W, j.B, j.R ? j.R + (size_t)b*IMG : nullptr,
               j.bng, j.bnb, bninv, j.O + (size_t)b*IMG, j.flags,
               blockIdx.y*64, blockIdx.x*64, lds);
}

// ---------- sscm attention weights [h][b][d] ----------
__global__ __launch_bounds__(64) void k_sscm_attn(SAJobs jo)
{
    const int br = blockIdx.y;
    const int h = blockIdx.x >> 3, b = blockIdx.x & 7, c = threadIdx.x;
    const int ci = c*8 + h;
    float qc = jo.q8[br][b*512 + ci];
    float s[8];
    #pragma unroll
    for (int d = 0; d < 8; d++){
        float p = qc * jo.k8[br][d*512 + ci];
        p = wave_sum(p);
        s[d] = p * 0.125f;
    }
    float m = s[0];
    #pragma unroll
    for (int d = 1; d < 8; d++) m = fmaxf(m, s[d]);
    float sum = 0.f;
    #pragma unroll
    for (int d = 0; d < 8; d++){ s[d] = __expf(s[d]-m); sum += s[d]; }
    float r = 1.f/sum;
    if (c < 8){
        float v = s[0];
        #pragma unroll
        for (int d = 1; d < 8; d++) if (c == d) v = s[d];
        jo.aw[br][blockIdx.x*8 + c] = v*r;
    }
}

// ---------- sscm apply ----------
__global__ __launch_bounds__(256) void k_sscm_apply(SPJobs jo)
{
    const int br = blockIdx.y;
    const int idx = blockIdx.x*256 + threadIdx.x;
    const int pix = idx & 255, e = (idx >> 8) & 511, b = idx >> 17;
    const int h = e & 7;
    const float* aw = jo.aw[br] + (h*8 + b)*8;
    const float* v = jo.v[br];
    float acc = 0.f;
    #pragma unroll
    for (int d = 0; d < 8; d++) acc += aw[d] * v[(size_t)d*IMG + (size_t)e*256 + pix];
    jo.out[br][idx] = acc;
}

// ---------- pixel cross-batch attention: MFMA (proven round 6), now pair-launchable ----------
__global__ __launch_bounds__(256) void k_pixel_mfma(PixJobs jo)
{
    __shared__ char smem[61440];
    unsigned short* sQh = (unsigned short*)smem;      // [2 ks][64 q][40]
    unsigned short* sQl = sQh + 2*64*40;
    unsigned short* sKh = sQl + 2*64*40;              // [2 ks][128 m][40]
    unsigned short* sKl = sKh + 2*128*40;
    unsigned short* sP  = (unsigned short*)smem;      // [4 ks][64 q][40]
    unsigned short* sVh = sP  + 4*64*40;              // [4 ks][64 c][40]
    unsigned short* sVl = sVh + 4*64*40;

    const int br = blockIdx.y >> 3, b = blockIdx.y & 7;
    const PixJob J = jo.j[br];
    const int nt = blockIdx.x & 3, d = blockIdx.x >> 2;
    const int h = blockIdx.z;
    const int tid = threadIdx.x;
    const int wv = tid >> 6, lane = tid & 63;
    const int quad = lane >> 4, l16 = lane & 15;
    const int n0 = nt * 64;
    const size_t bQ = (size_t)b * IMG;
    const size_t bK = (size_t)d * IMG;

    {
        const int q = tid & 63, c0 = tid >> 6;
        #pragma unroll
        for (int r = 0; r < 16; r++){
            int c = c0 + 4*r;
            float v = J.Q[bQ + (size_t)(c*8+h)*256 + n0 + q];
            unsigned short hi = bf16_rn(v);
            unsigned short lo = bf16_rn(v - bf16_to_f(hi));
            int idx = (c>>5)*2560 + q*40 + (c&31);
            sQh[idx] = hi; sQl[idx] = lo;
        }
    }
    {
        const int mloc = tid & 127, cb0 = tid >> 7;
        #pragma unroll
        for (int p = 0; p < 4; p++){
            int cb = cb0 + 2*p;
            short8 hi8, lo8;
            #pragma unroll
            for (int j = 0; j < 8; j++){
                float v = J.K[bK + (size_t)((cb*8+j)*8+h)*256 + mloc];
                unsigned short hv = bf16_rn(v);
                hi8[j] = (short)hv;
                lo8[j] = (short)bf16_rn(v - bf16_to_f(hv));
            }
            int idx = (cb>>2)*5120 + mloc*40 + (cb&3)*8;
            *(short8*)&sKh[idx] = hi8;
            *(short8*)&sKl[idx] = lo8;
        }
    }
    __syncthreads();

    short8 bqh[2], bql[2];
    #pragma unroll
    for (int ks = 0; ks < 2; ks++){
        int idx = ks*2560 + (wv*16 + l16)*40 + quad*8;
        bqh[ks] = *(const short8*)&sQh[idx];
        bql[ks] = *(const short8*)&sQl[idx];
    }

    f32x4 S[16] = {};
    #pragma unroll
    for (int hm = 0; hm < 2; hm++){
        if (hm == 1){
            __syncthreads();
            const int mloc = tid & 127, cb0 = tid >> 7;
            #pragma unroll
            for (int p = 0; p < 4; p++){
                int cb = cb0 + 2*p;
                short8 hi8, lo8;
                #pragma unroll
                for (int j = 0; j < 8; j++){
                    float v = J.K[bK + (size_t)((cb*8+j)*8+h)*256 + 128 + mloc];
                    unsigned short hv = bf16_rn(v);
                    hi8[j] = (short)hv;
                    lo8[j] = (short)bf16_rn(v - bf16_to_f(hv));
                }
                int idx = (cb>>2)*5120 + mloc*40 + (cb&3)*8;
                *(short8*)&sKh[idx] = hi8;
                *(short8*)&sKl[idx] = lo8;
            }
            __syncthreads();
        }
        #pragma unroll
        for (int mtl = 0; mtl < 8; mtl++){
            #pragma unroll
            for (int ks = 0; ks < 2; ks++){
                int idx = ks*5120 + (mtl*16 + l16)*40 + quad*8;
                short8 ah = *(const short8*)&sKh[idx];
                short8 al = *(const short8*)&sKl[idx];
                S[hm*8+mtl] = __builtin_amdgcn_mfma_f32_16x16x32_bf16(ah, bqh[ks], S[hm*8+mtl], 0, 0, 0);
                S[hm*8+mtl] = __builtin_amdgcn_mfma_f32_16x16x32_bf16(ah, bql[ks], S[hm*8+mtl], 0, 0, 0);
                S[hm*8+mtl] = __builtin_amdgcn_mfma_f32_16x16x32_bf16(al, bqh[ks], S[hm*8+mtl], 0, 0, 0);
            }
        }
    }

    {
        float mx = -3.4e38f;
        #pragma unroll
        for (int t = 0; t < 16; t++)
            #pragma unroll
            for (int r = 0; r < 4; r++) mx = fmaxf(mx, S[t][r]);
        mx = fmaxf(mx, __shfl_xor(mx, 16));
        mx = fmaxf(mx, __shfl_xor(mx, 32));
        float sum = 0.f;
        #pragma unroll
        for (int t = 0; t < 16; t++)
            #pragma unroll
            for (int r = 0; r < 4; r++){ S[t][r] = __expf(S[t][r]-mx); sum += S[t][r]; }
        sum += __shfl_xor(sum, 16);
        sum += __shfl_xor(sum, 32);
        float rr = 1.f/sum;
        #pragma unroll
        for (int t = 0; t < 16; t++)
            #pragma unroll
            for (int r = 0; r < 4; r++) S[t][r] *= rr;
    }
    __syncthreads();

    f32x4 oac[4] = {};
    #pragma unroll
    for (int hm = 0; hm < 2; hm++){
        #pragma unroll
        for (int mtl = 0; mtl < 8; mtl++){
            short4v p4;
            #pragma unroll
            for (int r = 0; r < 4; r++) p4[r] = (short)bf16_rn(S[hm*8+mtl][r]);
            int idx = (mtl>>1)*2560 + (wv*16 + l16)*40 + 16*(mtl&1) + quad*4;
            *(short4v*)&sP[idx] = p4;
        }
        {
            const int mp = tid & 63, c0 = tid >> 6;
            #pragma unroll
            for (int p = 0; p < 16; p++){
                int c = c0 + 4*p;
                float2 vv = *(const float2*)&J.V[bK + (size_t)(c*8+h)*256 + hm*128 + 2*mp];
                unsigned short h0 = bf16_rn(vv.x), h1 = bf16_rn(vv.y);
                unsigned short g0 = bf16_rn(vv.x - bf16_to_f(h0));
                unsigned short g1 = bf16_rn(vv.y - bf16_to_f(h1));
                int idx = (mp>>4)*2560 + c*40 + ((2*mp)&31);
                *(unsigned*)&sVh[idx] = (unsigned)h0 | ((unsigned)h1 << 16);
                *(unsigned*)&sVl[idx] = (unsigned)g0 | ((unsigned)g1 << 16);
            }
        }
        __syncthreads();
        #pragma unroll
        for (int ks = 0; ks < 4; ks++){
            int pidx = ks*2560 + (wv*16 + l16)*40 + quad*8;
            short8 bp = *(const short8*)&sP[pidx];
            #pragma unroll
            for (int ct = 0; ct < 4; ct++){
                int vidx = ks*2560 + (ct*16 + l16)*40 + quad*8;
                short8 vh = *(const short8*)&sVh[vidx];
                short8 vl = *(const short8*)&sVl[vidx];
                oac[ct] = __builtin_amdgcn_mfma_f32_16x16x32_bf16(vh, bp, oac[ct], 0, 0, 0);
                oac[ct] = __builtin_amdgcn_mfma_f32_16x16x32_bf16(vl, bp, oac[ct], 0, 0, 0);
            }
        }
        __syncthreads();
    }

    const int q = n0 + wv*16 + l16;
    #pragma unroll
    for (int ct = 0; ct < 4; ct++){
        #pragma unroll
        for (int r = 0; r < 4; r++){
            int c = ct*16 + quad*4 + r;
            unsafeAtomicAdd(&J.O[bQ + (size_t)(c*8+h)*256 + q], oac[ct][r]);
        }
    }
}

// ---------- LN over channels (strided), keeps [b][c][n] layout ----------
__global__ __launch_bounds__(64) void k_ln_pix(LnJobs jo,
    const float* __restrict__ g, const float* __restrict__ be)
{
    const int br = blockIdx.y;
    const int bn = blockIdx.x;
    const int b = bn >> 8, n = bn & 255;
    const int lane = threadIdx.x;
    const float* p = jo.in[br] + (size_t)b*IMG + n;
    float v[8]; float s = 0.f;
    #pragma unroll
    for (int i = 0; i < 8; i++){ v[i] = p[(size_t)(lane + 64*i)*256]; s += v[i]; }
    s = wave_sum(s);
    float mean = s * (1.f/512.f);
    float q = 0.f;
    #pragma unroll
    for (int i = 0; i < 8; i++){ float d = v[i]-mean; q += d*d; }
    q = wave_sum(q);
    float rstd = rsqrtf(q*(1.f/512.f) + 1e-5f);
    #pragma unroll
    for (int i = 0; i < 8; i++){
        int c = lane + 64*i;
        jo.out[br][(size_t)b*IMG + (size_t)c*256 + n] = (v[i]-mean)*rstd*g[c] + be[c];
    }
}

// ---------- host orchestration ----------
extern "C" void kernel_launch(void* const* d_in, const int* in_sizes, int n_in,
                              void* d_out, int out_size, void* d_ws, size_t ws_size,
                              hipStream_t stream)
{
    const float* xs    = (const float*)d_in[0];
    const float* xq    = (const float*)d_in[1];
    const float* qkvw  = (const float*)d_in[2];  const float* qkvb = (const float*)d_in[3];
    const float* paw   = (const float*)d_in[4];  const float* pab  = (const float*)d_in[5];
    const float* ln1g  = (const float*)d_in[6];  const float* ln1b = (const float*)d_in[7];
    const float* f1w   = (const float*)d_in[8];  const float* f1b  = (const float*)d_in[9];
    const float* f2w   = (const float*)d_in[10]; const float* f2b  = (const float*)d_in[11];
    const float* ln2g  = (const float*)d_in[12]; const float* ln2b = (const float*)d_in[13];
    const float* c1w   = (const float*)d_in[14]; const float* c1b  = (const float*)d_in[15];
    const float* c2w   = (const float*)d_in[16]; const float* c2b  = (const float*)d_in[17];
    const float* bng   = (const float*)d_in[18]; const float* bnb  = (const float*)d_in[19];
    const float* caqw  = (const float*)d_in[20]; const float* caqb = (const float*)d_in[21];
    const float* cakw  = (const float*)d_in[22]; const float* cakb = (const float*)d_in[23];
    const float* cavw  = (const float*)d_in[24]; const float* cavb = (const float*)d_in[25];
    const float* capw  = (const float*)d_in[26]; const float* capb = (const float*)d_in[27];
    const float* pqw   = (const float*)d_in[28]; const float* pqb  = (const float*)d_in[29];
    const float* pkw   = (const float*)d_in[30]; const float* pkb  = (const float*)d_in[31];
    const float* pvw   = (const float*)d_in[32]; const float* pvb  = (const float*)d_in[33];
    const float* ppw   = (const float*)d_in[34]; const float* ppb  = (const float*)d_in[35];
    const float* plng  = (const float*)d_in[36]; const float* plnb = (const float*)d_in[37];
    const float* plinw = (const float*)d_in[38]; const float* plinb= (const float*)d_in[39];

    const size_t SMF = 262144;  // small-scratch floats (2 branch regions of 131072)
    float* ws = (float*)d_ws;
    float* smb = ws;
    float* B[12];
    for (int i = 0; i < 12; i++) B[i] = ws + SMF + (size_t)i*BIGF;
    float* sa_s = B[0]; float* sa_q = B[1];
    float* ca_s = B[2]; float* ca_q = B[3];
    const bool paired_pixel = ws_size >= (SMF + 12*(size_t)BIGF)*sizeof(float) + 1024;

    auto SM = [&](int br){ return smb + (size_t)br*131072; };
    // per-branch small offsets
    auto GAP=[&](int br){ return SM(br); };            auto QKV=[&](int br){ return SM(br)+4096; };
    auto OM =[&](int br){ return SM(br)+20480; };      auto AA =[&](int br){ return SM(br)+24576; };
    auto HB =[&](int br){ return SM(br)+28672; };      auto A2 =[&](int br){ return SM(br)+32768; };
    auto LNB=[&](int br){ return SM(br)+36864; };      auto S8 =[&](int br){ return SM(br)+40960; };
    auto ATW=[&](int br){ return SM(br)+106496; };     auto Q8 =[&](int br){ return SM(br)+107008; };
    auto K8 =[&](int br){ return SM(br)+111104; };

    const float bninv = 1.0f / sqrtf(1.0f + 1e-5f);
    float* out0 = (float*)d_out;
    float* out1 = out0 + (size_t)BIGF;

    // ================= ASRI (both branches paired) =================
    {
        GapJobs gj = {{xs, xq}, {GAP(0), GAP(1)}};
        k_gap<<<dim3(4096,2), 64, 0, stream>>>(gj);
        G8Jobs qj = {{{GAP(0), qkvw, qkvb, nullptr, QKV(0)}, {GAP(1), qkvw, qkvb, nullptr, QKV(1)}}};
        k_gemm8<<<dim3(2048,2), 64, 0, stream>>>(qj, 0, 0, 2048, 0);
        AAJobs aj = {{QKV(0), QKV(1)}, {OM(0), OM(1)}};
        k_asri_attn<<<dim3(64,2), 64, 0, stream>>>(aj);
        G8Jobs pj = {{{OM(0), paw, pab, QKV(0), AA(0)}, {OM(1), paw, pab, QKV(1), AA(1)}}};
        k_gemm8<<<dim3(512,2), 64, 0, stream>>>(pj, 1536, 2048, 512, 0);
        LnJobs l1 = {{AA(0), AA(1)}, {LNB(0), LNB(1)}};
        k_ln8<<<dim3(8,2), 64, 0, stream>>>(l1, ln1g, ln1b);
        G8Jobs fj = {{{LNB(0), f1w, f1b, nullptr, HB(0)}, {LNB(1), f1w, f1b, nullptr, HB(1)}}};
        k_gemm8<<<dim3(512,2), 64, 0, stream>>>(fj, 0, 0, 512, 1);
        G8Jobs f2j = {{{HB(0), f2w, f2b, AA(0), A2(0)}, {HB(1), f2w, f2b, AA(1), A2(1)}}};
        k_gemm8<<<dim3(512,2), 64, 0, stream>>>(f2j, 0, 512, 512, 0);
        LnJobs l2 = {{A2(0), A2(1)}, {LNB(0), LNB(1)}};
        k_ln8<<<dim3(8,2), 64, 0, stream>>>(l2, ln2g, ln2b);
        G8Jobs cj = {{{LNB(0), c1w, c1b, nullptr, S8(0)}, {LNB(1), c1w, c1b, nullptr, S8(1)}}};
        k_gemm8<<<dim3(8192,2), 64, 0, stream>>>(cj, 0, 0, 8192, 0);
        UpJobs uj = {{S8(0), S8(1)}, {B[4], B[5]}};
        k_up<<<dim3(4096,2), 256, 0, stream>>>(uj);
        ConvJobs c2j = {};
        c2j.j[0] = {B[4], c2w, c2b, xs, bng, bnb, sa_s, CF_BN|CF_RELU|CF_RES};
        c2j.j[1] = {B[5], c2w, c2b, xq, bng, bnb, sa_q, CF_BN|CF_RELU|CF_RES};
        k_convm<<<dim3(4,8,16), 512, 0, stream>>>(c2j, bninv);
    }

    // ================= SSCM (both branches paired) =================
    {
        GapJobs gj = {{sa_s, sa_q}, {GAP(0), GAP(1)}};   // gap0 = gap(sa_s), gap1 = gap(sa_q)
        k_gap<<<dim3(4096,2), 64, 0, stream>>>(gj);
        G8Jobs qj = {{{GAP(0), caqw, caqb, nullptr, Q8(0)},   // br0: q from sa_s
                      {GAP(1), cakw, cakb, nullptr, K8(0)},   // br0: k from sa_q
                      {GAP(1), caqw, caqb, nullptr, Q8(1)},   // br1: q from sa_q
                      {GAP(0), cakw, cakb, nullptr, K8(1)}}}; // br1: k from sa_s
        k_gemm8<<<dim3(512,4), 64, 0, stream>>>(qj, 0, 0, 512, 0);
        SAJobs sj = {{Q8(0), Q8(1)}, {K8(0), K8(1)}, {ATW(0), ATW(1)}};
        k_sscm_attn<<<dim3(64,2), 64, 0, stream>>>(sj);
        ConvJobs vj = {};
        vj.j[0] = {sa_q, cavw, cavb, nullptr, nullptr, nullptr, B[4], 0};
        vj.j[1] = {sa_s, cavw, cavb, nullptr, nullptr, nullptr, B[5], 0};
        k_convm<<<dim3(4,8,16), 512, 0, stream>>>(vj, 1.f);
        SPJobs pj = {{ATW(0), ATW(1)}, {B[4], B[5]}, {B[6], B[7]}};
        k_sscm_apply<<<dim3(4096,2), 256, 0, stream>>>(pj);
        ConvJobs aj = {};
        aj.j[0] = {B[6], capw, capb, nullptr, nullptr, nullptr, ca_s, CF_RELU};
        aj.j[1] = {B[7], capw, capb, nullptr, nullptr, nullptr, ca_q, CF_RELU};
        k_convm<<<dim3(4,8,16), 512, 0, stream>>>(aj, 1.f);
    }

    // ================= PIXEL =================
    if (paired_pixel){
        ConvJobs qkvj = {};
        qkvj.j[0] = {sa_s, pqw, pqb, nullptr, nullptr, nullptr, B[4],  0};
        qkvj.j[1] = {ca_q, pkw, pkb, nullptr, nullptr, nullptr, B[5],  0};
        qkvj.j[2] = {ca_q, pvw, pvb, nullptr, nullptr, nullptr, B[6],  0};
        qkvj.j[3] = {sa_q, pqw, pqb, nullptr, nullptr, nullptr, B[8],  0};
        qkvj.j[4] = {ca_s, pkw, pkb, nullptr, nullptr, nullptr, B[9],  0};
        qkvj.j[5] = {ca_s, pvw, pvb, nullptr, nullptr, nullptr, B[10], 0};
        k_convm<<<dim3(4,8,48), 512, 0, stream>>>(qkvj, 1.f);
        ZJobs zj = {{B[7], B[11]}};
        k_zero<<<dim3(4096,2), 256, 0, stream>>>(zj);
        PixJobs pxj = {{{B[4], B[5], B[6], B[7]}, {B[8], B[9], B[10], B[11]}}};
        k_pixel_mfma<<<dim3(32,16,8), 256, 0, stream>>>(pxj);
        ConvJobs ppj = {};
        ppj.j[0] = {B[7],  ppw, ppb, sa_s, nullptr, nullptr, out0, CF_RES};
        ppj.j[1] = {B[11], ppw, ppb, sa_q, nullptr, nullptr, out1, CF_RES};
        k_convm<<<dim3(4,8,16), 512, 0, stream>>>(ppj, 1.f);
        LnJobs lj = {{out0, out1}, {B[4], B[8]}};
        k_ln_pix<<<dim3(2048,2), 64, 0, stream>>>(lj, plng, plnb);
        ConvJobs lnj = {};
        lnj.j[0] = {B[4], plinw, plinb, nullptr, nullptr, nullptr, out0, CF_RELU};
        lnj.j[1] = {B[8], plinw, plinb, nullptr, nullptr, nullptr, out1, CF_RELU};
        k_convm<<<dim3(4,8,16), 512, 0, stream>>>(lnj, 1.f);
    } else {
        auto pixel1 = [&](const float* x1, const float* x2, float* out){
            ConvJobs qkvj = {};
            qkvj.j[0] = {x1, pqw, pqb, nullptr, nullptr, nullptr, B[4], 0};
            qkvj.j[1] = {x2, pkw, pkb, nullptr, nullptr, nullptr, B[5], 0};
            qkvj.j[2] = {x2, pvw, pvb, nullptr, nullptr, nullptr, B[6], 0};
            k_convm<<<dim3(4,8,24), 512, 0, stream>>>(qkvj, 1.f);
            ZJobs zj = {{B[7], B[7]}};
            k_zero<<<dim3(4096,1), 256, 0, stream>>>(zj);
            PixJobs pxj = {{{B[4], B[5], B[6], B[7]}, {B[4], B[5], B[6], B[7]}}};
            k_pixel_mfma<<<dim3(32,8,8), 256, 0, stream>>>(pxj);
            ConvJobs ppj = {};
            ppj.j[0] = {B[7], ppw, ppb, x1, nullptr, nullptr, out, CF_RES};
            k_convm<<<dim3(4,8,8), 512, 0, stream>>>(ppj, 1.f);
            LnJobs lj = {{out, out}, {B[4], B[4]}};
            k_ln_pix<<<dim3(2048,1), 64, 0, stream>>>(lj, plng, plnb);
            ConvJobs lnj = {};
            lnj.j[0] = {B[4], plinw, plinb, nullptr, nullptr, nullptr, out, CF_RELU};
            k_convm<<<dim3(4,8,8), 512, 0, stream>>>(lnj, 1.f);
        };
        pixel1(sa_s, ca_q, out0);
        pixel1(sa_q, ca_s, out1);
    }

    (void)in_sizes; (void)n_in; (void)out_size;
}